// Round 17
// baseline (449.620 us; speedup 1.0000x reference)
//
#include <hip/hip_runtime.h>
#include <math.h>
#include <stdio.h>

// EdgewiseMSA: B=2, N=1024, DIM=512, H=8, DK=64, HIDDEN=16
// R17: gating conv1/conv2 via MFMA (they ARE matmuls: 6->16->4 per element).
// Per 32 elements: 1 mfma (W1[16x6+bias] x feat) -> gelu full-wave (8/lane)
// -> half-swap shfl_xor(32) -> cvt_pk_bf16 -> 1 mfma (W2 rows duplicated so
// both lane-halves hold gates; b2 via C operand) -> scalar tail. Fragment
// mappings per verified guide (m74/m101). Rest byte-identical to R16.

typedef unsigned short u16;
typedef __attribute__((ext_vector_type(8))) short short8;
typedef __attribute__((ext_vector_type(4))) short short4v;
typedef __attribute__((ext_vector_type(4))) float f32x4;
typedef __attribute__((ext_vector_type(16))) float f32x16;

#define DEVI static __device__ __forceinline__

DEVI float bf2f(u16 u){ union{unsigned v; float f;} x; x.v = ((unsigned)u)<<16u; return x.f; }
DEVI u16 f2bf(float f){ union{float f; unsigned v;} x; x.f=f; unsigned r = x.v + 0x7FFFu + ((x.v>>16)&1u); return (u16)(r>>16); }

DEVI void gload_lds16(const u16* gptr, u16* lptr){
  __builtin_amdgcn_global_load_lds(
      (const __attribute__((address_space(1))) void*)gptr,
      (__attribute__((address_space(3))) void*)lptr,
      16, 0, 0);
}

enum { EPI_F32=0, EPI_BF16=1, EPI_LOGBF16=2, EPI_BF16T=3, EPI_QKV=4, EPI_Y=5, EPI_YADD=6 };

// C[r][c] = sum_k A[r][k] * Bt[c][k].  BMxBN tile, 4 waves (WR x WC), BK=64.
// 32x32x16 MFMA; LDS: linear dest for global_load_lds + XOR-swizzled content.
template<int BM,int BN,int WR,int WC,int EPI>
__global__ __launch_bounds__(256) void gemm_bt(
    const u16* __restrict__ A, const u16* __restrict__ B,
    void* __restrict__ p0, void* __restrict__ p1, void* __restrict__ p2,
    const float* __restrict__ logit,
    int K, int lda, int ldb,
    long long sA, long long sB, long long sC, int ldc)
{
  constexpr int WM = BM/WR, WN = BN/WC;
  constexpr int MB = WM/32, NB = WN/32;   // 32x32 fragment blocks per wave
  constexpr int BK = 64;
  __shared__ u16 As[BM][BK];
  __shared__ u16 Bs[BN][BK];
  const int z = blockIdx.z;
  const u16* Ap = A + (long long)z*sA;
  const u16* Bp = B + (long long)z*sB;
  const int r0 = blockIdx.y*BM, c0 = blockIdx.x*BN;
  const int tid = threadIdx.x;
  const int wave = tid>>6, lane = tid&63;
  const int wr = (wave/WC)*WM, wc = (wave%WC)*WN;
  const int lrow = lane&31;            // fragment row (A) / col (B,C)
  const int kby  = (lane>>5)*16;       // k byte offset within 16-wide k-group
  const int l8 = lane>>3, l7 = lane&7;
  const int scol = ((l7 ^ l8) * 8);    // pre-swizzled source column (elements)

  f32x16 acc[MB][NB] = {};

  for (int k0=0; k0<K; k0+=BK){
    __syncthreads();
    #pragma unroll
    for (int i=0;i<BM/32;i++){
      int ins = wave + 4*i;
      int row = ins*8 + l8;
      gload_lds16(&Ap[(long long)(r0+row)*lda + k0 + scol], &As[ins*8][0]);
    }
    #pragma unroll
    for (int i=0;i<BN/32;i++){
      int ins = wave + 4*i;
      int row = ins*8 + l8;
      gload_lds16(&Bp[(long long)(c0+row)*ldb + k0 + scol], &Bs[ins*8][0]);
    }
    __syncthreads();
    #pragma unroll
    for (int kk=0; kk<4; ++kk){        // 4 x K=16 substeps per BK=64
      short8 af[MB], bfr[NB];
      #pragma unroll
      for (int m=0;m<MB;m++){
        int R = wr + m*32 + lrow;
        int eo = ((kk*32 + kby) ^ ((R&7)<<4)) >> 1;   // swizzled u16 offset
        af[m] = *(const short8*)&As[R][eo];
      }
      #pragma unroll
      for (int n=0;n<NB;n++){
        int R = wc + n*32 + lrow;
        int eo = ((kk*32 + kby) ^ ((R&7)<<4)) >> 1;
        bfr[n] = *(const short8*)&Bs[R][eo];
      }
      #pragma unroll
      for (int m=0;m<MB;m++)
        #pragma unroll
        for (int n=0;n<NB;n++)
          acc[m][n] = __builtin_amdgcn_mfma_f32_32x32x16_bf16(af[m], bfr[n], acc[m][n], 0,0,0);
    }
  }

  float yscale = 0.f;
  if constexpr (EPI==EPI_YADD) yscale = 1.f/(1.f+expf(-logit[0]));

  #pragma unroll
  for (int m=0;m<MB;m++)
   #pragma unroll
   for (int n=0;n<NB;n++)
    #pragma unroll
    for (int reg=0;reg<16;reg++){
      int r = r0 + wr + m*32 + (reg&3) + 8*(reg>>2) + 4*(lane>>5);
      int c = c0 + wc + n*32 + lrow;
      float v = acc[m][n][reg];
      if constexpr (EPI==EPI_F32){
        ((float*)p0)[(long long)z*sC + (long long)r*ldc + c] = v;
      } else if constexpr (EPI==EPI_BF16){
        ((u16*)p0)[(long long)z*sC + (long long)r*ldc + c] = f2bf(v);
      } else if constexpr (EPI==EPI_LOGBF16){
        ((u16*)p0)[(long long)z*sC + (long long)r*ldc + c] = f2bf(__logf(v + 1e-6f));
      } else if constexpr (EPI==EPI_BF16T){
        ((u16*)p0)[(long long)z*sC + (long long)c*ldc + r] = f2bf(v);
      } else if constexpr (EPI==EPI_QKV){
        int b = r>>10, n_ = r&1023;
        int which = c>>9, h = (c>>6)&7, d = c&63;
        long long bh = (long long)b*8 + h;
        if (which==0)      ((u16*)p0)[(bh*1024 + n_)*64 + d] = f2bf(v*0.125f);
        else if (which==1) ((u16*)p1)[(bh*1024 + n_)*64 + d] = f2bf(v);
        else               ((u16*)p2)[(bh*64 + d)*1024 + n_] = f2bf(v);
      } else if constexpr (EPI==EPI_Y){
        int b = z>>3, h = z&7;
        ((u16*)p0)[((long long)(b*1024 + r))*512 + h*64 + c] = f2bf(v);
      } else if constexpr (EPI==EPI_YADD){
        int b = z>>3, h = z&7;
        long long idx = ((long long)(b*1024 + r))*512 + h*64 + c;
        u16* yb = (u16*)p0;
        yb[idx] = f2bf(bf2f(yb[idx]) + yscale*v);
      }
    }
}

// row softmax over 1024 cols; src bf16; dst bf16
template<int SRC_BF16>
__global__ __launch_bounds__(256) void softmax_rows(const void* __restrict__ Sv, u16* __restrict__ A)
{
  const long long row = blockIdx.x;
  const int tid = threadIdx.x;
  float v[4];
  if constexpr (SRC_BF16){
    const u16* s = (const u16*)Sv + row*1024;
    short4v x = *(const short4v*)&s[tid*4];
    #pragma unroll
    for (int i=0;i<4;i++) v[i] = bf2f((u16)x[i]);
  } else {
    const float* s = (const float*)Sv + row*1024;
    f32x4 x = *(const f32x4*)&s[tid*4];
    #pragma unroll
    for (int i=0;i<4;i++) v[i] = x[i];
  }
  __shared__ float red[4];
  float m = fmaxf(fmaxf(v[0],v[1]),fmaxf(v[2],v[3]));
  #pragma unroll
  for (int off=32; off>0; off>>=1) m = fmaxf(m, __shfl_xor(m, off, 64));
  if ((tid&63)==0) red[tid>>6] = m;
  __syncthreads();
  m = fmaxf(fmaxf(red[0],red[1]),fmaxf(red[2],red[3]));
  float e[4], sum=0.f;
  #pragma unroll
  for (int i=0;i<4;i++){ e[i] = __expf(v[i]-m); sum += e[i]; }
  #pragma unroll
  for (int off=32; off>0; off>>=1) sum += __shfl_xor(sum, off, 64);
  __syncthreads();
  if ((tid&63)==0) red[tid>>6] = sum;
  __syncthreads();
  float inv = 1.f/(red[0]+red[1]+red[2]+red[3]);
  u16* a = A + row*1024;
  short4v o;
  #pragma unroll
  for (int i=0;i<4;i++) o[i] = (short)f2bf(e[i]*inv);
  *(short4v*)&a[tid*4] = o;
}

// 1024x1024 bf16 transpose per z
__global__ __launch_bounds__(256) void transpose_bf16(const u16* __restrict__ in, u16* __restrict__ out)
{
  __shared__ u16 tile[32][33];
  const long long base = (long long)blockIdx.z*1024*1024;
  const int xb = blockIdx.x*32, yb = blockIdx.y*32;
  const int tx = threadIdx.x&31, ty = threadIdx.x>>5;
  #pragma unroll
  for (int rr=0;rr<4;rr++){
    int i = ty + rr*8;
    tile[i][tx] = in[base + (long long)(yb+i)*1024 + xb+tx];
  }
  __syncthreads();
  #pragma unroll
  for (int rr=0;rr<4;rr++){
    int i = ty + rr*8;
    out[base + (long long)(xb+i)*1024 + yb+tx] = tile[tx][i];
  }
}

__global__ __launch_bounds__(256) void cast_f32_bf16(const float* __restrict__ in, u16* __restrict__ out, int n4)
{
  int i = blockIdx.x*256 + threadIdx.x;
  if (i < n4){
    f32x4 x = ((const f32x4*)in)[i];
    short4v o;
    #pragma unroll
    for (int j=0;j<4;j++) o[j] = (short)f2bf(x[j]);
    ((short4v*)out)[i] = o;
  }
}

// out[c][r] = bf16(in[r][c]); in: rows x cols (f32)
__global__ __launch_bounds__(256) void castT_f32_bf16(const float* __restrict__ in, u16* __restrict__ out, int rows, int cols)
{
  __shared__ float tile[32][33];
  const int cb = blockIdx.x*32, rb = blockIdx.y*32;
  const int tx = threadIdx.x&31, ty = threadIdx.x>>5;
  #pragma unroll
  for (int rr=0;rr<4;rr++){
    int i = ty + rr*8;
    tile[i][tx] = in[(long long)(rb+i)*cols + cb+tx];
  }
  __syncthreads();
  #pragma unroll
  for (int rr=0;rr<4;rr++){
    int i = ty + rr*8;
    out[(long long)(cb+i)*rows + rb+tx] = f2bf(tile[tx][i]);
  }
}

// gating + Smix -> Smix bf16 via MFMA conv layers.
// Wave pipeline (one 32-col tile row): lane e assembles element e's feat
// (k=0..5 feats, k=6 bias-one; lanes 32-63 zero) -> mfma(W1f, ff) ->
// gelu on 8 valid h regs/lane -> half-swap -> cvt_pk bf16 -> mfma(W2f, hf,
// C=b2) -> gates in regs 0-3 (both halves) -> scalar tail -> store (lanes<32).
__global__ __launch_bounds__(256) void gating_kernel(
    const u16* __restrict__ S0, const u16* __restrict__ S1,
    const u16* __restrict__ CR, const u16* __restrict__ CL,
    const float* __restrict__ w1, const float* __restrict__ b1,
    const float* __restrict__ w2, const float* __restrict__ b2,
    u16* __restrict__ Smix)
{
  __shared__ u16 t0[32][33], t1[32][33], t0t[32][33], t1t[32][33];
  const int tid = threadIdx.x;
  const long long base = (long long)blockIdx.z*1024*1024;
  const int rb = blockIdx.y*32, cb = blockIdx.x*32;
  const int tx = tid&31, ty = tid>>5;
  #pragma unroll
  for (int rr=0;rr<4;rr++){
    int i = ty + rr*8;
    t0 [i][tx] = S0[base + (long long)(rb+i)*1024 + cb+tx];
    t1 [i][tx] = S1[base + (long long)(rb+i)*1024 + cb+tx];
    t0t[i][tx] = S0[base + (long long)(cb+i)*1024 + rb+tx];
    t1t[i][tx] = S1[base + (long long)(cb+i)*1024 + rb+tx];
  }
  __syncthreads();

  const int lane = tid & 63;
  const int wv   = tid >> 6;     // wave 0..3 -> rows 8w..8w+7
  const int e    = lane & 31;    // element (column) index
  const int kg   = lane >> 5;    // k-group: 0 -> k0-7, 1 -> k8-15

  // W1 fragment: row=hidden(e), k=(kg*8+j). k=0..5 weights, k=6 bias, else 0.
  short8 w1f = {};
  if (kg==0 && e<16){
    #pragma unroll
    for (int k=0;k<6;k++) w1f[k] = (short)f2bf(w1[e*6+k]);
    w1f[6] = (short)0x3F80 ? (short)f2bf(b1[e]) : 0; // bias at k=6
  }
  // W2 fragment: rows 0-3 = gates, rows 4-7 duplicated gates (so high lanes
  // of D2 also hold gates); k split by kg.
  short8 w2f = {};
  if (e<8){
    #pragma unroll
    for (int k=0;k<8;k++) w2f[k] = (short)f2bf(w2[(e&3)*16 + kg*8 + k]);
  }
  // C operand for conv2: regs 0-3 = b2[j] (rows j+4*kg, both map to gate j).
  f32x16 c2init = {};
  c2init[0]=b2[0]; c2init[1]=b2[1]; c2init[2]=b2[2]; c2init[3]=b2[3];
  const f32x16 zero16 = {};

  #pragma unroll 1
  for (int p=0;p<8;p++){
    const int r = wv*8 + p;
    long long off = base + (long long)(rb+r)*1024 + cb+e;
    u16 s0u = t0[r][e], s1u = t1[r][e];
    u16 crU = CR[off], clU = CL[off];
    short8 ff = {};
    if (kg==0){
      ff[0]=(short)s0u; ff[1]=(short)s1u;
      ff[2]=(short)t0t[e][r]; ff[3]=(short)t1t[e][r];
      ff[4]=(short)crU; ff[5]=(short)clU;
      ff[6]=(short)0x3F80;            // 1.0 (bias multiplier)
    }
    f32x16 hD = __builtin_amdgcn_mfma_f32_32x32x16_bf16(w1f, ff, zero16, 0,0,0);
    // valid h: low lanes regs0-7 = h0-3,h8-11; high lanes = h4-7,h12-15
    float hv[8];
    #pragma unroll
    for (int j=0;j<8;j++){
      float xx = hD[j];
      float zv = 1.5957691f*fmaf(0.044715f*xx*xx, xx, xx);
      zv = fminf(3.0f, fmaxf(-3.0f, zv));
      float pp = fmaf(zv, fmaf(zv*zv, -0.011008f, 0.25f), 0.5f);
      hv[j] = xx*pp;
    }
    // half-swap: low needs high's hv[0..3] (=h4-7); high needs low's hv[4..7] (=h8-11)
    float ex0[4], ex1[4];
    #pragma unroll
    for (int j=0;j<4;j++){ ex0[j] = __shfl_xor(hv[j], 32, 64); ex1[j] = __shfl_xor(hv[4+j], 32, 64); }
    float q[8];
    #pragma unroll
    for (int j=0;j<4;j++){
      q[j]   = kg ? ex1[j] : hv[j];    // low: h0-3   ; high: h8-11
      q[4+j] = kg ? hv[4+j] : ex0[j];  // low: h4-7   ; high: h12-15
    }
    unsigned hw0,hw1,hw2,hw3;
    asm("v_cvt_pk_bf16_f32 %0, %1, %2" : "=v"(hw0) : "v"(q[0]), "v"(q[1]));
    asm("v_cvt_pk_bf16_f32 %0, %1, %2" : "=v"(hw1) : "v"(q[2]), "v"(q[3]));
    asm("v_cvt_pk_bf16_f32 %0, %1, %2" : "=v"(hw2) : "v"(q[4]), "v"(q[5]));
    asm("v_cvt_pk_bf16_f32 %0, %1, %2" : "=v"(hw3) : "v"(q[6]), "v"(q[7]));
    short8 hf;
    hf[0]=(short)(hw0&0xFFFF); hf[1]=(short)(hw0>>16);
    hf[2]=(short)(hw1&0xFFFF); hf[3]=(short)(hw1>>16);
    hf[4]=(short)(hw2&0xFFFF); hf[5]=(short)(hw2>>16);
    hf[6]=(short)(hw3&0xFFFF); hf[7]=(short)(hw3>>16);
    f32x16 gD = __builtin_amdgcn_mfma_f32_32x32x16_bf16(w2f, hf, c2init, 0,0,0);
    float E0=__expf(gD[0]), E1=__expf(gD[1]), E2=__expf(gD[2]), E3=__expf(gD[3]);
    float g0=E0*(1.f-E0), g1=E1*(1.f-E1), g2=E2*(1.f-E2), g3=E3*(1.f-E3);
    float s0 = bf2f(s0u), s1v = bf2f(s1u), cr = bf2f(crU);
    float mx = fmaxf(s0,s1v);
    float ee = __expf(-fabsf(s0-s1v));
    float lse = mx + __logf(1.f + ee);
    float smix = s0 + g0*s1v + g1*(lse-s0) - g2*(0.5f*s1v) + g3*cr;
    if (kg==0) Smix[off] = f2bf(smix);
    (void)clU;
  }
}

extern "C" void kernel_launch(void* const* d_in, const int* in_sizes, int n_in,
                              void* d_out, int out_size, void* d_ws, size_t ws_size,
                              hipStream_t stream)
{
  const float* x     = (const float*)d_in[0];
  const float* Wqkv0 = (const float*)d_in[1];
  const float* Wqkv1 = (const float*)d_in[2];
  const float* Wproj = (const float*)d_in[3];
  const float* c1w   = (const float*)d_in[4];
  const float* c1b   = (const float*)d_in[5];
  const float* c2w   = (const float*)d_in[6];
  const float* c2b   = (const float*)d_in[7];
  const float* logit = (const float*)d_in[8];

  char* ws = (char*)d_ws;
  size_t off = 0;
  auto alloc = [&](size_t bytes)->char*{ char* p = ws + off; off = (off + bytes + 255) & ~(size_t)255; return p; };

  const long long NN16 = 16LL*1024*1024;
  u16* xb  = (u16*)alloc(2048LL*512*2);
  u16* w0T = (u16*)alloc(1536LL*512*2);
  u16* w1T = (u16*)alloc(1536LL*512*2);
  u16* wpT = (u16*)alloc(512LL*512*2);
  u16* q0  = (u16*)alloc(16LL*1024*64*2);
  u16* k0  = (u16*)alloc(16LL*1024*64*2);
  u16* v0T = (u16*)alloc(16LL*1024*64*2);
  u16* q1  = (u16*)alloc(16LL*1024*64*2);
  u16* k1  = (u16*)alloc(16LL*1024*64*2);
  u16* v1T = (u16*)alloc(16LL*1024*64*2);
  u16* S0b = (u16*)alloc(NN16*2);   // reused as Ab after gating
  u16* S1b = (u16*)alloc(NN16*2);
  u16* A0  = (u16*)alloc(NN16*2);
  u16* A1  = (u16*)alloc(NN16*2);
  u16* A0T = (u16*)alloc(NN16*2);   // reused as CR after CL GEMM
  u16* A1T = (u16*)alloc(NN16*2);   // reused as Smix after CR GEMM
  u16* CL  = (u16*)alloc(NN16*2);
  u16* tT  = (u16*)alloc(16LL*64*1024*2);
  u16* Yb  = (u16*)alloc(2048LL*512*2);

  u16* CR   = A0T;
  u16* Smix = A1T;
  u16* Ab   = S0b;

  if (off > ws_size){
    fprintf(stderr, "kernel_launch: ws too small: need %zu have %zu\n", off, ws_size);
    return;
  }

  dim3 blk(256);

  // 1. input casts / transposed weight casts
  cast_f32_bf16<<<dim3(262144/256), blk, 0, stream>>>(x, xb, 262144);
  castT_f32_bf16<<<dim3(48,16), blk, 0, stream>>>(Wqkv0, w0T, 512, 1536);
  castT_f32_bf16<<<dim3(48,16), blk, 0, stream>>>(Wqkv1, w1T, 512, 1536);
  castT_f32_bf16<<<dim3(16,16), blk, 0, stream>>>(Wproj, wpT, 512, 512);

  // 2. QKV projections
  gemm_bt<128,128,2,2,EPI_QKV><<<dim3(12,16,1), blk, 0, stream>>>(
      xb, w0T, q0, k0, v0T, nullptr, 512, 512, 512, 0,0, 0,0);
  gemm_bt<128,128,2,2,EPI_QKV><<<dim3(12,16,1), blk, 0, stream>>>(
      xb, w1T, q1, k1, v1T, nullptr, 512, 512, 512, 0,0, 0,0);

  // 3. S0, S1
  gemm_bt<128,128,2,2,EPI_BF16><<<dim3(8,8,16), blk, 0, stream>>>(
      q0, k0, S0b, nullptr, nullptr, nullptr, 64, 64, 64, 65536,65536, 1048576, 1024);
  gemm_bt<128,128,2,2,EPI_BF16><<<dim3(8,8,16), blk, 0, stream>>>(
      q1, k1, S1b, nullptr, nullptr, nullptr, 64, 64, 64, 65536,65536, 1048576, 1024);

  // 4. softmaxes
  softmax_rows<1><<<dim3(16384), blk, 0, stream>>>(S0b, A0);
  softmax_rows<1><<<dim3(16384), blk, 0, stream>>>(S1b, A1);

  // 5. transposes
  transpose_bf16<<<dim3(32,32,16), blk, 0, stream>>>(A0, A0T);
  transpose_bf16<<<dim3(32,32,16), blk, 0, stream>>>(A1, A1T);

  // 6. Cli then Cri (frees A0T for CR)
  gemm_bt<128,128,2,2,EPI_LOGBF16><<<dim3(8,8,16), blk, 0, stream>>>(
      A1, A0T, CL, nullptr, nullptr, nullptr, 1024, 1024, 1024, 1048576,1048576, 1048576, 1024);
  gemm_bt<128,128,2,2,EPI_LOGBF16><<<dim3(8,8,16), blk, 0, stream>>>(
      A0, A1T, CR, nullptr, nullptr, nullptr, 1024, 1024, 1024, 1048576,1048576, 1048576, 1024);

  // 7. gating -> Smix
  gating_kernel<<<dim3(32,32,16), blk, 0, stream>>>(S0b, S1b, CR, CL, c1w, c1b, c2w, c2b, Smix);

  // 8. A = softmax(Smix)
  softmax_rows<1><<<dim3(16384), blk, 0, stream>>>(Smix, Ab);

  // 9. t = A1@v1 (tT), y = A@v0 -> Yb (bf16), y += sig*A0@t (bf16 rmw)
  gemm_bt<64,64,2,2,EPI_BF16T><<<dim3(1,16,16), blk, 0, stream>>>(
      A1, v1T, tT, nullptr, nullptr, nullptr, 1024, 1024, 1024, 1048576,65536, 65536, 1024);
  gemm_bt<64,64,2,2,EPI_Y><<<dim3(1,16,16), blk, 0, stream>>>(
      Ab, v0T, Yb, nullptr, nullptr, nullptr, 1024, 1024, 1024, 1048576,65536, 0, 0);
  gemm_bt<64,64,2,2,EPI_YADD><<<dim3(1,16,16), blk, 0, stream>>>(
      A0, tT, Yb, nullptr, nullptr, logit, 1024, 1024, 1024, 1048576,65536, 0, 0);

  // 10. out = Y @ Wproj
  gemm_bt<64,64,2,2,EPI_F32><<<dim3(8,32,1), blk, 0, stream>>>(
      Yb, wpT, d_out, nullptr, nullptr, nullptr, 512, 512, 512, 0,0, 0, 512);

  (void)in_sizes; (void)n_in; (void)out_size;
}

// Round 18
// 400.717 us; speedup vs baseline: 1.1220x; 1.1220x over previous
//
#include <hip/hip_runtime.h>
#include <math.h>
#include <stdio.h>

// EdgewiseMSA: B=2, N=1024, DIM=512, H=8, DK=64, HIDDEN=16
// R18: R17 MFMA-gating regressed (155us: VALU 124%, shuffle+pack overhead) ->
// gating reverted to R13 (129us floor, 5 structures probed). New: graph-level
// merges. (1) Y+YADD fused into one dual-K GEMM (ys folded into tT epilogue,
// no bf16 RMW). (2) z-merged dispatch pairs: QKV(w0|w1), S(S0|S1),
// softmax(A0|A1), transpose(A0|A1), castT(w0|w1). CL/CR stay sequential
// (CR output aliases A0T which CL reads). 19 -> 14 dispatches.

typedef unsigned short u16;
typedef __attribute__((ext_vector_type(8))) short short8;
typedef __attribute__((ext_vector_type(4))) short short4v;
typedef __attribute__((ext_vector_type(4))) float f32x4;
typedef __attribute__((ext_vector_type(2))) float f32x2;
typedef __attribute__((ext_vector_type(16))) float f32x16;

#define DEVI static __device__ __forceinline__

DEVI float bf2f(u16 u){ union{unsigned v; float f;} x; x.v = ((unsigned)u)<<16u; return x.f; }
DEVI u16 f2bf(float f){ union{float f; unsigned v;} x; x.f=f; unsigned r = x.v + 0x7FFFu + ((x.v>>16)&1u); return (u16)(r>>16); }

DEVI f32x2 bc(float s){ f32x2 r; r[0]=s; r[1]=s; return r; }
DEVI f32x2 pkfma(f32x2 a, f32x2 b, f32x2 c){ return __builtin_elementwise_fma(a,b,c); }
DEVI f32x2 pkmin(f32x2 a, f32x2 b){ return __builtin_elementwise_min(a,b); }
DEVI f32x2 pkmax(f32x2 a, f32x2 b){ return __builtin_elementwise_max(a,b); }

DEVI void gload_lds16(const u16* gptr, u16* lptr){
  __builtin_amdgcn_global_load_lds(
      (const __attribute__((address_space(1))) void*)gptr,
      (__attribute__((address_space(3))) void*)lptr,
      16, 0, 0);
}

enum { EPI_F32=0, EPI_BF16=1, EPI_LOGBF16=2, EPI_BF16T=3, EPI_QKV=4, EPI_Y=5 };
// MODE: 0 = single; 1 = z-split (z>=zsplit uses A2/B2 and p0b/p1b/p2b);
//       2 = dual-K (acc += A@B then += A2@B2; one epilogue).

template<int BM,int BN,int WR,int WC,int EPI,int MODE>
__global__ __launch_bounds__(256) void gemm_bt(
    const u16* __restrict__ A, const u16* __restrict__ B,
    const u16* __restrict__ A2, const u16* __restrict__ B2,
    void* __restrict__ p0, void* __restrict__ p1, void* __restrict__ p2,
    void* __restrict__ p0b, void* __restrict__ p1b, void* __restrict__ p2b,
    const float* __restrict__ logit,
    int K, int lda, int ldb,
    long long sA, long long sB, long long sC, int ldc, int zsplit)
{
  constexpr int WM = BM/WR, WN = BN/WC;
  constexpr int MB = WM/32, NB = WN/32;
  constexpr int BK = 64;
  __shared__ u16 As[BM][BK];
  __shared__ u16 Bs[BN][BK];
  const int z = blockIdx.z;
  const bool sec = (MODE==1) && (z >= zsplit);
  const int ze = sec ? z - zsplit : z;
  const u16* Ap = (sec ? A2 : A) + (long long)ze*sA;
  const u16* Bp = (sec ? B2 : B) + (long long)ze*sB;
  void* o0 = sec ? p0b : p0;
  void* o1 = sec ? p1b : p1;
  void* o2 = sec ? p2b : p2;
  const int r0 = blockIdx.y*BM, c0 = blockIdx.x*BN;
  const int tid = threadIdx.x;
  const int wave = tid>>6, lane = tid&63;
  const int wr = (wave/WC)*WM, wc = (wave%WC)*WN;
  const int lrow = lane&31;
  const int kby  = (lane>>5)*16;
  const int l8 = lane>>3, l7 = lane&7;
  const int scol = ((l7 ^ l8) * 8);

  f32x16 acc[MB][NB] = {};

  auto kloop = [&](const u16* AP, const u16* BP){
    for (int k0=0; k0<K; k0+=BK){
      __syncthreads();
      #pragma unroll
      for (int i=0;i<BM/32;i++){
        int ins = wave + 4*i;
        int row = ins*8 + l8;
        gload_lds16(&AP[(long long)(r0+row)*lda + k0 + scol], &As[ins*8][0]);
      }
      #pragma unroll
      for (int i=0;i<BN/32;i++){
        int ins = wave + 4*i;
        int row = ins*8 + l8;
        gload_lds16(&BP[(long long)(c0+row)*ldb + k0 + scol], &Bs[ins*8][0]);
      }
      __syncthreads();
      #pragma unroll
      for (int kk=0; kk<4; ++kk){
        short8 af[MB], bfr[NB];
        #pragma unroll
        for (int m=0;m<MB;m++){
          int R = wr + m*32 + lrow;
          int eo = ((kk*32 + kby) ^ ((R&7)<<4)) >> 1;
          af[m] = *(const short8*)&As[R][eo];
        }
        #pragma unroll
        for (int n=0;n<NB;n++){
          int R = wc + n*32 + lrow;
          int eo = ((kk*32 + kby) ^ ((R&7)<<4)) >> 1;
          bfr[n] = *(const short8*)&Bs[R][eo];
        }
        #pragma unroll
        for (int m=0;m<MB;m++)
          #pragma unroll
          for (int n=0;n<NB;n++)
            acc[m][n] = __builtin_amdgcn_mfma_f32_32x32x16_bf16(af[m], bfr[n], acc[m][n], 0,0,0);
      }
    }
  };

  kloop(Ap, Bp);
  if constexpr (MODE==2){
    kloop(A2 + (long long)z*sA, B2 + (long long)z*sB);
  }

  float tscale = 1.f;
  if constexpr (EPI==EPI_BF16T){ if (logit) tscale = 1.f/(1.f+expf(-logit[0])); }

  #pragma unroll
  for (int m=0;m<MB;m++)
   #pragma unroll
   for (int n=0;n<NB;n++)
    #pragma unroll
    for (int reg=0;reg<16;reg++){
      int r = r0 + wr + m*32 + (reg&3) + 8*(reg>>2) + 4*(lane>>5);
      int c = c0 + wc + n*32 + lrow;
      float v = acc[m][n][reg];
      if constexpr (EPI==EPI_F32){
        ((float*)o0)[(long long)z*sC + (long long)r*ldc + c] = v;
      } else if constexpr (EPI==EPI_BF16){
        ((u16*)o0)[(long long)ze*sC + (long long)r*ldc + c] = f2bf(v);
      } else if constexpr (EPI==EPI_LOGBF16){
        ((u16*)o0)[(long long)z*sC + (long long)r*ldc + c] = f2bf(__logf(v + 1e-6f));
      } else if constexpr (EPI==EPI_BF16T){
        ((u16*)o0)[(long long)z*sC + (long long)c*ldc + r] = f2bf(v*tscale);
      } else if constexpr (EPI==EPI_QKV){
        int b = r>>10, n_ = r&1023;
        int which = c>>9, h = (c>>6)&7, d = c&63;
        long long bh = (long long)b*8 + h;
        if (which==0)      ((u16*)o0)[(bh*1024 + n_)*64 + d] = f2bf(v*0.125f);
        else if (which==1) ((u16*)o1)[(bh*1024 + n_)*64 + d] = f2bf(v);
        else               ((u16*)o2)[(bh*64 + d)*1024 + n_] = f2bf(v);
      } else if constexpr (EPI==EPI_Y){
        int b = z>>3, h = z&7;
        ((u16*)o0)[((long long)(b*1024 + r))*512 + h*64 + c] = f2bf(v);
      }
    }
}

// row softmax over 1024 cols, two sources merged; src/dst bf16
__global__ __launch_bounds__(256) void softmax_rows2(
    const u16* __restrict__ s0, u16* __restrict__ d0,
    const u16* __restrict__ s1, u16* __restrict__ d1, int half)
{
  const int b = blockIdx.x;
  const u16* s; u16* a;
  if (b < half){ s = s0 + (long long)b*1024;        a = d0 + (long long)b*1024; }
  else         { s = s1 + (long long)(b-half)*1024; a = d1 + (long long)(b-half)*1024; }
  const int tid = threadIdx.x;
  short4v x = *(const short4v*)&s[tid*4];
  float v[4];
  #pragma unroll
  for (int i=0;i<4;i++) v[i] = bf2f((u16)x[i]);
  __shared__ float red[4];
  float m = fmaxf(fmaxf(v[0],v[1]),fmaxf(v[2],v[3]));
  #pragma unroll
  for (int off=32; off>0; off>>=1) m = fmaxf(m, __shfl_xor(m, off, 64));
  if ((tid&63)==0) red[tid>>6] = m;
  __syncthreads();
  m = fmaxf(fmaxf(red[0],red[1]),fmaxf(red[2],red[3]));
  float e[4], sum=0.f;
  #pragma unroll
  for (int i=0;i<4;i++){ e[i] = __expf(v[i]-m); sum += e[i]; }
  #pragma unroll
  for (int off=32; off>0; off>>=1) sum += __shfl_xor(sum, off, 64);
  __syncthreads();
  if ((tid&63)==0) red[tid>>6] = sum;
  __syncthreads();
  float inv = 1.f/(red[0]+red[1]+red[2]+red[3]);
  short4v o;
  #pragma unroll
  for (int i=0;i<4;i++) o[i] = (short)f2bf(e[i]*inv);
  *(short4v*)&a[tid*4] = o;
}

// 1024x1024 bf16 transpose, two tensors merged over z (z<16: in0->out0)
__global__ __launch_bounds__(256) void transpose_bf16_2(
    const u16* __restrict__ in0, u16* __restrict__ out0,
    const u16* __restrict__ in1, u16* __restrict__ out1)
{
  __shared__ u16 tile[32][33];
  const int z = blockIdx.z;
  const u16* in  = (z<16) ? in0  : in1;
  u16* out       = (z<16) ? out0 : out1;
  const long long base = (long long)(z&15)*1024*1024;
  const int xb = blockIdx.x*32, yb = blockIdx.y*32;
  const int tx = threadIdx.x&31, ty = threadIdx.x>>5;
  #pragma unroll
  for (int rr=0;rr<4;rr++){
    int i = ty + rr*8;
    tile[i][tx] = in[base + (long long)(yb+i)*1024 + xb+tx];
  }
  __syncthreads();
  #pragma unroll
  for (int rr=0;rr<4;rr++){
    int i = ty + rr*8;
    out[base + (long long)(xb+i)*1024 + yb+tx] = tile[tx][i];
  }
}

__global__ __launch_bounds__(256) void cast_f32_bf16(const float* __restrict__ in, u16* __restrict__ out, int n4)
{
  int i = blockIdx.x*256 + threadIdx.x;
  if (i < n4){
    f32x4 x = ((const f32x4*)in)[i];
    short4v o;
    #pragma unroll
    for (int j=0;j<4;j++) o[j] = (short)f2bf(x[j]);
    ((short4v*)out)[i] = o;
  }
}

// out[c][r] = bf16(in[r][c]); two matrices merged via z
__global__ __launch_bounds__(256) void castT_f32_bf16_2(
    const float* __restrict__ in0, u16* __restrict__ out0,
    const float* __restrict__ in1, u16* __restrict__ out1, int rows, int cols)
{
  __shared__ float tile[32][33];
  const float* in = blockIdx.z ? in1 : in0;
  u16* out        = blockIdx.z ? out1 : out0;
  const int cb = blockIdx.x*32, rb = blockIdx.y*32;
  const int tx = threadIdx.x&31, ty = threadIdx.x>>5;
  #pragma unroll
  for (int rr=0;rr<4;rr++){
    int i = ty + rr*8;
    tile[i][tx] = in[(long long)(rb+i)*cols + cb+tx];
  }
  __syncthreads();
  #pragma unroll
  for (int rr=0;rr<4;rr++){
    int i = ty + rr*8;
    out[(long long)(cb+i)*rows + rb+tx] = f2bf(tile[tx][i]);
  }
}

__global__ __launch_bounds__(256) void castT_f32_bf16(const float* __restrict__ in, u16* __restrict__ out, int rows, int cols)
{
  __shared__ float tile[32][33];
  const int cb = blockIdx.x*32, rb = blockIdx.y*32;
  const int tx = threadIdx.x&31, ty = threadIdx.x>>5;
  #pragma unroll
  for (int rr=0;rr<4;rr++){
    int i = ty + rr*8;
    tile[i][tx] = in[(long long)(rb+i)*cols + cb+tx];
  }
  __syncthreads();
  #pragma unroll
  for (int rr=0;rr<4;rr++){
    int i = ty + rr*8;
    out[(long long)(cb+i)*rows + rb+tx] = f2bf(tile[tx][i]);
  }
}

// gating + Smix -> Smix bf16 (R13 exact: packed f32 via builtins, cubic
// sigmoid gelu, gates sigma(a)=e^a(1-e^a), o-loop unroll 4). 129us measured.
__global__ __launch_bounds__(256) void gating_kernel(
    const u16* __restrict__ S0, const u16* __restrict__ S1,
    const u16* __restrict__ CR, const u16* __restrict__ CL,
    const float* __restrict__ w1, const float* __restrict__ b1,
    const float* __restrict__ w2, const float* __restrict__ b2,
    u16* __restrict__ Smix)
{
  __shared__ float t0[32][33], t1[32][33], t0t[32][33], t1t[32][33];
  const int tid = threadIdx.x;
  const long long base = (long long)blockIdx.z*1024*1024;
  const int rb = blockIdx.y*32, cb = blockIdx.x*32;
  const int tx = tid&31, ty = tid>>5;
  #pragma unroll
  for (int rr=0;rr<4;rr++){
    int i = ty + rr*8;
    t0 [i][tx] = bf2f(S0[base + (long long)(rb+i)*1024 + cb+tx]);
    t1 [i][tx] = bf2f(S1[base + (long long)(rb+i)*1024 + cb+tx]);
    t0t[i][tx] = bf2f(S0[base + (long long)(cb+i)*1024 + rb+tx]);
    t1t[i][tx] = bf2f(S1[base + (long long)(cb+i)*1024 + rb+tx]);
  }
  __syncthreads();
  #pragma unroll 1
  for (int rr=0;rr<2;rr++){
    const int i0 = ty + rr*16, i1 = i0 + 8;
    f32x2 s0, s1v, s0t, s1t, cr, cl;
    s0[0]  = t0 [i0][tx]; s0[1]  = t0 [i1][tx];
    s1v[0] = t1 [i0][tx]; s1v[1] = t1 [i1][tx];
    s0t[0] = t0t[tx][i0]; s0t[1] = t0t[tx][i1];
    s1t[0] = t1t[tx][i0]; s1t[1] = t1t[tx][i1];
    long long off0 = base + (long long)(rb+i0)*1024 + cb+tx;
    long long off1 = base + (long long)(rb+i1)*1024 + cb+tx;
    cr[0] = bf2f(CR[off0]); cr[1] = bf2f(CR[off1]);
    cl[0] = bf2f(CL[off0]); cl[1] = bf2f(CL[off1]);
    f32x2 a0 = bc(b2[0]), a1 = bc(b2[1]), a2 = bc(b2[2]), a3 = bc(b2[3]);
    #pragma unroll 4
    for (int o=0;o<16;o++){
      f32x2 xx = pkfma(bc(w1[o*6+0]), s0,  bc(b1[o]));
      xx = pkfma(bc(w1[o*6+1]), s1v, xx);
      xx = pkfma(bc(w1[o*6+2]), s0t, xx);
      xx = pkfma(bc(w1[o*6+3]), s1t, xx);
      xx = pkfma(bc(w1[o*6+4]), cr,  xx);
      xx = pkfma(bc(w1[o*6+5]), cl,  xx);
      f32x2 xx2 = xx*xx;
      f32x2 u   = pkfma(bc(0.044715f), xx2, bc(1.f));
      f32x2 zz  = (xx*u) * bc(1.5957691f);
      zz = pkmin(pkmax(zz, bc(-3.f)), bc(3.f));
      f32x2 w   = pkfma(bc(-0.011008f), zz*zz, bc(0.25f));
      f32x2 p   = pkfma(zz, w, bc(0.5f));
      f32x2 hh  = xx*p;
      a0 = pkfma(bc(w2[o]),    hh, a0);
      a1 = pkfma(bc(w2[16+o]), hh, a1);
      a2 = pkfma(bc(w2[32+o]), hh, a2);
      a3 = pkfma(bc(w2[48+o]), hh, a3);
    }
    f32x2 g0, g1, g2, g3;
    { float E;
      E=__expf(a0[0]); g0[0]=E*(1.f-E);  E=__expf(a0[1]); g0[1]=E*(1.f-E);
      E=__expf(a1[0]); g1[0]=E*(1.f-E);  E=__expf(a1[1]); g1[1]=E*(1.f-E);
      E=__expf(a2[0]); g2[0]=E*(1.f-E);  E=__expf(a2[1]); g2[1]=E*(1.f-E);
      E=__expf(a3[0]); g3[0]=E*(1.f-E);  E=__expf(a3[1]); g3[1]=E*(1.f-E);
    }
    f32x2 mx = pkmax(s0, s1v);
    f32x2 dd = s0 - s1v;
    f32x2 ad = pkmax(dd, bc(0.f)-dd);
    f32x2 ee, lg;
    ee[0] = __expf(-ad[0]); ee[1] = __expf(-ad[1]);
    lg[0] = __logf(1.f+ee[0]); lg[1] = __logf(1.f+ee[1]);
    f32x2 lse = mx + lg;
    f32x2 smix = s0 + g0*s1v + g1*(lse - s0) - g2*(bc(0.5f)*s1v) + g3*cr;
    Smix[off0] = f2bf(smix[0]);
    Smix[off1] = f2bf(smix[1]);
  }
}

extern "C" void kernel_launch(void* const* d_in, const int* in_sizes, int n_in,
                              void* d_out, int out_size, void* d_ws, size_t ws_size,
                              hipStream_t stream)
{
  const float* x     = (const float*)d_in[0];
  const float* Wqkv0 = (const float*)d_in[1];
  const float* Wqkv1 = (const float*)d_in[2];
  const float* Wproj = (const float*)d_in[3];
  const float* c1w   = (const float*)d_in[4];
  const float* c1b   = (const float*)d_in[5];
  const float* c2w   = (const float*)d_in[6];
  const float* c2b   = (const float*)d_in[7];
  const float* logit = (const float*)d_in[8];

  char* ws = (char*)d_ws;
  size_t off = 0;
  auto alloc = [&](size_t bytes)->char*{ char* p = ws + off; off = (off + bytes + 255) & ~(size_t)255; return p; };

  const long long NN16 = 16LL*1024*1024;
  u16* xb  = (u16*)alloc(2048LL*512*2);
  u16* w0T = (u16*)alloc(1536LL*512*2);
  u16* w1T = (u16*)alloc(1536LL*512*2);
  u16* wpT = (u16*)alloc(512LL*512*2);
  u16* q0  = (u16*)alloc(16LL*1024*64*2);
  u16* k0  = (u16*)alloc(16LL*1024*64*2);
  u16* v0T = (u16*)alloc(16LL*1024*64*2);
  u16* q1  = (u16*)alloc(16LL*1024*64*2);
  u16* k1  = (u16*)alloc(16LL*1024*64*2);
  u16* v1T = (u16*)alloc(16LL*1024*64*2);
  u16* S0b = (u16*)alloc(NN16*2);   // reused as Ab after gating
  u16* S1b = (u16*)alloc(NN16*2);
  u16* A0  = (u16*)alloc(NN16*2);
  u16* A1  = (u16*)alloc(NN16*2);
  u16* A0T = (u16*)alloc(NN16*2);   // reused as CR after CL GEMM
  u16* A1T = (u16*)alloc(NN16*2);   // reused as Smix after CR GEMM
  u16* CL  = (u16*)alloc(NN16*2);
  u16* tT  = (u16*)alloc(16LL*64*1024*2);
  u16* Yb  = (u16*)alloc(2048LL*512*2);

  u16* CR   = A0T;
  u16* Smix = A1T;
  u16* Ab   = S0b;

  if (off > ws_size){
    fprintf(stderr, "kernel_launch: ws too small: need %zu have %zu\n", off, ws_size);
    return;
  }

  dim3 blk(256);

  // 1. casts (x; w0T|w1T merged; wpT)
  cast_f32_bf16<<<dim3(262144/256), blk, 0, stream>>>(x, xb, 262144);
  castT_f32_bf16_2<<<dim3(48,16,2), blk, 0, stream>>>(Wqkv0, w0T, Wqkv1, w1T, 512, 1536);
  castT_f32_bf16<<<dim3(16,16), blk, 0, stream>>>(Wproj, wpT, 512, 512);

  // 2. QKV projections, both weight sets in one dispatch (z=0/1)
  gemm_bt<128,128,2,2,EPI_QKV,1><<<dim3(12,16,2), blk, 0, stream>>>(
      xb, w0T, xb, w1T, q0, k0, v0T, q1, k1, v1T, nullptr,
      512, 512, 512, 0, 0, 0, 0, 1);

  // 3. S0|S1 in one dispatch (z<16: S0, z>=16: S1)
  gemm_bt<128,128,2,2,EPI_BF16,1><<<dim3(8,8,32), blk, 0, stream>>>(
      q0, k0, q1, k1, S0b, nullptr, nullptr, S1b, nullptr, nullptr, nullptr,
      64, 64, 64, 65536, 65536, 1048576, 1024, 16);

  // 4. softmax A0|A1 in one dispatch
  softmax_rows2<<<dim3(32768), blk, 0, stream>>>(S0b, A0, S1b, A1, 16384);

  // 5. transposes A0|A1 in one dispatch
  transpose_bf16_2<<<dim3(32,32,32), blk, 0, stream>>>(A0, A0T, A1, A1T);

  // 6. Cli then Cri (sequential: CR output aliases A0T which CL reads)
  gemm_bt<128,128,2,2,EPI_LOGBF16,0><<<dim3(8,8,16), blk, 0, stream>>>(
      A1, A0T, nullptr, nullptr, CL, nullptr, nullptr, nullptr, nullptr, nullptr, nullptr,
      1024, 1024, 1024, 1048576, 1048576, 1048576, 1024, 0);
  gemm_bt<128,128,2,2,EPI_LOGBF16,0><<<dim3(8,8,16), blk, 0, stream>>>(
      A0, A1T, nullptr, nullptr, CR, nullptr, nullptr, nullptr, nullptr, nullptr, nullptr,
      1024, 1024, 1024, 1048576, 1048576, 1048576, 1024, 0);

  // 7. gating -> Smix
  gating_kernel<<<dim3(32,32,16), blk, 0, stream>>>(S0b, S1b, CR, CL, c1w, c1b, c2w, c2b, Smix);

  // 8. A = softmax(Smix)
  softmax_rows2<<<dim3(16384), blk, 0, stream>>>(Smix, Ab, Smix, Ab, 16384);

  // 9. tT = ys * (A1 @ v1), transposed store (ys folded here)
  gemm_bt<64,64,2,2,EPI_BF16T,0><<<dim3(1,16,16), blk, 0, stream>>>(
      A1, v1T, nullptr, nullptr, tT, nullptr, nullptr, nullptr, nullptr, nullptr, logit,
      1024, 1024, 1024, 1048576, 65536, 65536, 1024, 0);

  // 10. Yb = Ab@v0T + A0@tT (dual-K, one epilogue, no RMW)
  gemm_bt<64,64,2,2,EPI_Y,2><<<dim3(1,16,16), blk, 0, stream>>>(
      Ab, v0T, A0, tT, Yb, nullptr, nullptr, nullptr, nullptr, nullptr, nullptr,
      1024, 1024, 1024, 1048576, 65536, 0, 0, 0);

  // 11. out = Y @ Wproj
  gemm_bt<64,64,2,2,EPI_F32,0><<<dim3(8,32,1), blk, 0, stream>>>(
      Yb, wpT, nullptr, nullptr, d_out, nullptr, nullptr, nullptr, nullptr, nullptr, nullptr,
      512, 512, 512, 0, 0, 0, 512, 0);

  (void)in_sizes; (void)n_in; (void)out_size;
}

// Round 19
// 382.940 us; speedup vs baseline: 1.1741x; 1.0464x over previous
//
#include <hip/hip_runtime.h>
#include <math.h>
#include <stdio.h>

// EdgewiseMSA: B=2, N=1024, DIM=512, H=8, DK=64, HIDDEN=16
// R19: fused softmax+transpose (softmaxT): one kernel reads S, writes A and
// A^T -- kills the 64MB A re-read and one dispatch (was softmax2 26us +
// transpose2 26us, both pure-BW). Gating stays R13 (129us = packed-VALU issue
// floor; R14 audit corrected: builtins DID emit v_pk, 8.6 inst/elem measured
// matches packed estimate). Rest identical to R18 (400.7us).

typedef unsigned short u16;
typedef __attribute__((ext_vector_type(8))) short short8;
typedef __attribute__((ext_vector_type(4))) short short4v;
typedef __attribute__((ext_vector_type(4))) float f32x4;
typedef __attribute__((ext_vector_type(2))) float f32x2;
typedef __attribute__((ext_vector_type(16))) float f32x16;

#define DEVI static __device__ __forceinline__

DEVI float bf2f(u16 u){ union{unsigned v; float f;} x; x.v = ((unsigned)u)<<16u; return x.f; }
DEVI u16 f2bf(float f){ union{float f; unsigned v;} x; x.f=f; unsigned r = x.v + 0x7FFFu + ((x.v>>16)&1u); return (u16)(r>>16); }

DEVI f32x2 bc(float s){ f32x2 r; r[0]=s; r[1]=s; return r; }
DEVI f32x2 pkfma(f32x2 a, f32x2 b, f32x2 c){ return __builtin_elementwise_fma(a,b,c); }
DEVI f32x2 pkmin(f32x2 a, f32x2 b){ return __builtin_elementwise_min(a,b); }
DEVI f32x2 pkmax(f32x2 a, f32x2 b){ return __builtin_elementwise_max(a,b); }

DEVI void gload_lds16(const u16* gptr, u16* lptr){
  __builtin_amdgcn_global_load_lds(
      (const __attribute__((address_space(1))) void*)gptr,
      (__attribute__((address_space(3))) void*)lptr,
      16, 0, 0);
}

enum { EPI_F32=0, EPI_BF16=1, EPI_LOGBF16=2, EPI_BF16T=3, EPI_QKV=4, EPI_Y=5 };
// MODE: 0 = single; 1 = z-split; 2 = dual-K (acc += A@B then += A2@B2).

template<int BM,int BN,int WR,int WC,int EPI,int MODE>
__global__ __launch_bounds__(256) void gemm_bt(
    const u16* __restrict__ A, const u16* __restrict__ B,
    const u16* __restrict__ A2, const u16* __restrict__ B2,
    void* __restrict__ p0, void* __restrict__ p1, void* __restrict__ p2,
    void* __restrict__ p0b, void* __restrict__ p1b, void* __restrict__ p2b,
    const float* __restrict__ logit,
    int K, int lda, int ldb,
    long long sA, long long sB, long long sC, int ldc, int zsplit)
{
  constexpr int WM = BM/WR, WN = BN/WC;
  constexpr int MB = WM/32, NB = WN/32;
  constexpr int BK = 64;
  __shared__ u16 As[BM][BK];
  __shared__ u16 Bs[BN][BK];
  const int z = blockIdx.z;
  const bool sec = (MODE==1) && (z >= zsplit);
  const int ze = sec ? z - zsplit : z;
  const u16* Ap = (sec ? A2 : A) + (long long)ze*sA;
  const u16* Bp = (sec ? B2 : B) + (long long)ze*sB;
  void* o0 = sec ? p0b : p0;
  void* o1 = sec ? p1b : p1;
  void* o2 = sec ? p2b : p2;
  const int r0 = blockIdx.y*BM, c0 = blockIdx.x*BN;
  const int tid = threadIdx.x;
  const int wave = tid>>6, lane = tid&63;
  const int wr = (wave/WC)*WM, wc = (wave%WC)*WN;
  const int lrow = lane&31;
  const int kby  = (lane>>5)*16;
  const int l8 = lane>>3, l7 = lane&7;
  const int scol = ((l7 ^ l8) * 8);

  f32x16 acc[MB][NB] = {};

  auto kloop = [&](const u16* AP, const u16* BP){
    for (int k0=0; k0<K; k0+=BK){
      __syncthreads();
      #pragma unroll
      for (int i=0;i<BM/32;i++){
        int ins = wave + 4*i;
        int row = ins*8 + l8;
        gload_lds16(&AP[(long long)(r0+row)*lda + k0 + scol], &As[ins*8][0]);
      }
      #pragma unroll
      for (int i=0;i<BN/32;i++){
        int ins = wave + 4*i;
        int row = ins*8 + l8;
        gload_lds16(&BP[(long long)(c0+row)*ldb + k0 + scol], &Bs[ins*8][0]);
      }
      __syncthreads();
      #pragma unroll
      for (int kk=0; kk<4; ++kk){
        short8 af[MB], bfr[NB];
        #pragma unroll
        for (int m=0;m<MB;m++){
          int R = wr + m*32 + lrow;
          int eo = ((kk*32 + kby) ^ ((R&7)<<4)) >> 1;
          af[m] = *(const short8*)&As[R][eo];
        }
        #pragma unroll
        for (int n=0;n<NB;n++){
          int R = wc + n*32 + lrow;
          int eo = ((kk*32 + kby) ^ ((R&7)<<4)) >> 1;
          bfr[n] = *(const short8*)&Bs[R][eo];
        }
        #pragma unroll
        for (int m=0;m<MB;m++)
          #pragma unroll
          for (int n=0;n<NB;n++)
            acc[m][n] = __builtin_amdgcn_mfma_f32_32x32x16_bf16(af[m], bfr[n], acc[m][n], 0,0,0);
      }
    }
  };

  kloop(Ap, Bp);
  if constexpr (MODE==2){
    kloop(A2 + (long long)z*sA, B2 + (long long)z*sB);
  }

  float tscale = 1.f;
  if constexpr (EPI==EPI_BF16T){ if (logit) tscale = 1.f/(1.f+expf(-logit[0])); }

  #pragma unroll
  for (int m=0;m<MB;m++)
   #pragma unroll
   for (int n=0;n<NB;n++)
    #pragma unroll
    for (int reg=0;reg<16;reg++){
      int r = r0 + wr + m*32 + (reg&3) + 8*(reg>>2) + 4*(lane>>5);
      int c = c0 + wc + n*32 + lrow;
      float v = acc[m][n][reg];
      if constexpr (EPI==EPI_F32){
        ((float*)o0)[(long long)z*sC + (long long)r*ldc + c] = v;
      } else if constexpr (EPI==EPI_BF16){
        ((u16*)o0)[(long long)ze*sC + (long long)r*ldc + c] = f2bf(v);
      } else if constexpr (EPI==EPI_LOGBF16){
        ((u16*)o0)[(long long)z*sC + (long long)r*ldc + c] = f2bf(__logf(v + 1e-6f));
      } else if constexpr (EPI==EPI_BF16T){
        ((u16*)o0)[(long long)z*sC + (long long)c*ldc + r] = f2bf(v*tscale);
      } else if constexpr (EPI==EPI_QKV){
        int b = r>>10, n_ = r&1023;
        int which = c>>9, h = (c>>6)&7, d = c&63;
        long long bh = (long long)b*8 + h;
        if (which==0)      ((u16*)o0)[(bh*1024 + n_)*64 + d] = f2bf(v*0.125f);
        else if (which==1) ((u16*)o1)[(bh*1024 + n_)*64 + d] = f2bf(v);
        else               ((u16*)o2)[(bh*64 + d)*1024 + n_] = f2bf(v);
      } else if constexpr (EPI==EPI_Y){
        int b = z>>3, h = z&7;
        ((u16*)o0)[((long long)(b*1024 + r))*512 + h*64 + c] = f2bf(v);
      }
    }
}

// fused row-softmax + transpose: reads S (32 rows/block), writes A and A^T.
// z<16: (Sa->Aa,ATa); z>=16: (Sb->Ab,ATb).
__global__ __launch_bounds__(256) void softmaxT(
    const u16* __restrict__ Sa, u16* __restrict__ Aa, u16* __restrict__ ATa,
    const u16* __restrict__ Sb, u16* __restrict__ Ab2, u16* __restrict__ ATb)
{
  __shared__ u16 tile[32][1032];   // +8 u16 pad keeps 16B row alignment
  const int zz = blockIdx.y;
  const long long nn = 1048576;
  const u16* S; u16 *A; u16 *AT;
  if (zz < 16){ S = Sa + (long long)zz*nn;      A = Aa  + (long long)zz*nn;      AT = ATa + (long long)zz*nn; }
  else        { S = Sb + (long long)(zz-16)*nn; A = Ab2 + (long long)(zz-16)*nn; AT = ATb + (long long)(zz-16)*nn; }
  const int rb = blockIdx.x*32;
  const int tid = threadIdx.x;

  // P0: coalesced load 32x1024
  #pragma unroll
  for (int i=0;i<16;i++){
    int f = tid + i*256;              // 4096 chunks of 8 elems
    int r = f>>7, c = (f&127)*8;
    *(short8*)&tile[r][c] = *(const short8*)&S[(long long)(rb+r)*1024 + c];
  }
  __syncthreads();

  const int row = ((tid>>6)<<3) + ((tid&63)>>3);  // wave*8 + (lane>>3)
  const int seg = tid&7;
  // P1: max over this lane's 128 elems, then 8-lane group reduce
  float m = -3.4e38f;
  #pragma unroll
  for (int j=0;j<16;j++){
    short8 x = *(const short8*)&tile[row][seg*128 + j*8];
    #pragma unroll
    for (int q=0;q<8;q++) m = fmaxf(m, bf2f((u16)x[q]));
  }
  m = fmaxf(m, __shfl_xor(m,1,64));
  m = fmaxf(m, __shfl_xor(m,2,64));
  m = fmaxf(m, __shfl_xor(m,4,64));
  // P2: sum of exp
  float s = 0.f;
  #pragma unroll
  for (int j=0;j<16;j++){
    short8 x = *(const short8*)&tile[row][seg*128 + j*8];
    #pragma unroll
    for (int q=0;q<8;q++) s += __expf(bf2f((u16)x[q]) - m);
  }
  s += __shfl_xor(s,1,64);
  s += __shfl_xor(s,2,64);
  s += __shfl_xor(s,4,64);
  float inv = 1.f/s;
  // P3: normalize in place
  #pragma unroll
  for (int j=0;j<16;j++){
    short8 x = *(const short8*)&tile[row][seg*128 + j*8];
    short8 o;
    #pragma unroll
    for (int q=0;q<8;q++) o[q] = (short)f2bf(__expf(bf2f((u16)x[q]) - m)*inv);
    *(short8*)&tile[row][seg*128 + j*8] = o;
  }
  __syncthreads();
  // P4: coalesced A write
  #pragma unroll
  for (int i=0;i<16;i++){
    int f = tid + i*256;
    int r = f>>7, c = (f&127)*8;
    *(short8*)&A[(long long)(rb+r)*1024 + c] = *(const short8*)&tile[r][c];
  }
  // P5: A^T write: thread handles 4 columns; each column = 32 u16 -> 64B store
  #pragma unroll
  for (int i=0;i<4;i++){
    int c = tid*4 + i;
    short8 o0, o1, o2, o3;
    #pragma unroll
    for (int q=0;q<8;q++){
      o0[q] = (short)tile[q][c];
      o1[q] = (short)tile[8+q][c];
      o2[q] = (short)tile[16+q][c];
      o3[q] = (short)tile[24+q][c];
    }
    u16* dst = &AT[(long long)c*1024 + rb];
    *(short8*)&dst[0]  = o0;
    *(short8*)&dst[8]  = o1;
    *(short8*)&dst[16] = o2;
    *(short8*)&dst[24] = o3;
  }
}

// row softmax over 1024 cols, two sources merged; src/dst bf16
__global__ __launch_bounds__(256) void softmax_rows2(
    const u16* __restrict__ s0, u16* __restrict__ d0,
    const u16* __restrict__ s1, u16* __restrict__ d1, int half)
{
  const int b = blockIdx.x;
  const u16* s; u16* a;
  if (b < half){ s = s0 + (long long)b*1024;        a = d0 + (long long)b*1024; }
  else         { s = s1 + (long long)(b-half)*1024; a = d1 + (long long)(b-half)*1024; }
  const int tid = threadIdx.x;
  short4v x = *(const short4v*)&s[tid*4];
  float v[4];
  #pragma unroll
  for (int i=0;i<4;i++) v[i] = bf2f((u16)x[i]);
  __shared__ float red[4];
  float m = fmaxf(fmaxf(v[0],v[1]),fmaxf(v[2],v[3]));
  #pragma unroll
  for (int off=32; off>0; off>>=1) m = fmaxf(m, __shfl_xor(m, off, 64));
  if ((tid&63)==0) red[tid>>6] = m;
  __syncthreads();
  m = fmaxf(fmaxf(red[0],red[1]),fmaxf(red[2],red[3]));
  float e[4], sum=0.f;
  #pragma unroll
  for (int i=0;i<4;i++){ e[i] = __expf(v[i]-m); sum += e[i]; }
  #pragma unroll
  for (int off=32; off>0; off>>=1) sum += __shfl_xor(sum, off, 64);
  __syncthreads();
  if ((tid&63)==0) red[tid>>6] = sum;
  __syncthreads();
  float inv = 1.f/(red[0]+red[1]+red[2]+red[3]);
  short4v o;
  #pragma unroll
  for (int i=0;i<4;i++) o[i] = (short)f2bf(e[i]*inv);
  *(short4v*)&a[tid*4] = o;
}

__global__ __launch_bounds__(256) void cast_f32_bf16(const float* __restrict__ in, u16* __restrict__ out, int n4)
{
  int i = blockIdx.x*256 + threadIdx.x;
  if (i < n4){
    f32x4 x = ((const f32x4*)in)[i];
    short4v o;
    #pragma unroll
    for (int j=0;j<4;j++) o[j] = (short)f2bf(x[j]);
    ((short4v*)out)[i] = o;
  }
}

// out[c][r] = bf16(in[r][c]); two matrices merged via z
__global__ __launch_bounds__(256) void castT_f32_bf16_2(
    const float* __restrict__ in0, u16* __restrict__ out0,
    const float* __restrict__ in1, u16* __restrict__ out1, int rows, int cols)
{
  __shared__ float tile[32][33];
  const float* in = blockIdx.z ? in1 : in0;
  u16* out        = blockIdx.z ? out1 : out0;
  const int cb = blockIdx.x*32, rb = blockIdx.y*32;
  const int tx = threadIdx.x&31, ty = threadIdx.x>>5;
  #pragma unroll
  for (int rr=0;rr<4;rr++){
    int i = ty + rr*8;
    tile[i][tx] = in[(long long)(rb+i)*cols + cb+tx];
  }
  __syncthreads();
  #pragma unroll
  for (int rr=0;rr<4;rr++){
    int i = ty + rr*8;
    out[(long long)(cb+i)*rows + rb+tx] = f2bf(tile[tx][i]);
  }
}

__global__ __launch_bounds__(256) void castT_f32_bf16(const float* __restrict__ in, u16* __restrict__ out, int rows, int cols)
{
  __shared__ float tile[32][33];
  const int cb = blockIdx.x*32, rb = blockIdx.y*32;
  const int tx = threadIdx.x&31, ty = threadIdx.x>>5;
  #pragma unroll
  for (int rr=0;rr<4;rr++){
    int i = ty + rr*8;
    tile[i][tx] = in[(long long)(rb+i)*cols + cb+tx];
  }
  __syncthreads();
  #pragma unroll
  for (int rr=0;rr<4;rr++){
    int i = ty + rr*8;
    out[(long long)(cb+i)*rows + rb+tx] = f2bf(tile[tx][i]);
  }
}

// gating + Smix -> Smix bf16 (R13 exact; 129us = packed issue floor).
__global__ __launch_bounds__(256) void gating_kernel(
    const u16* __restrict__ S0, const u16* __restrict__ S1,
    const u16* __restrict__ CR, const u16* __restrict__ CL,
    const float* __restrict__ w1, const float* __restrict__ b1,
    const float* __restrict__ w2, const float* __restrict__ b2,
    u16* __restrict__ Smix)
{
  __shared__ float t0[32][33], t1[32][33], t0t[32][33], t1t[32][33];
  const int tid = threadIdx.x;
  const long long base = (long long)blockIdx.z*1024*1024;
  const int rb = blockIdx.y*32, cb = blockIdx.x*32;
  const int tx = tid&31, ty = tid>>5;
  #pragma unroll
  for (int rr=0;rr<4;rr++){
    int i = ty + rr*8;
    t0 [i][tx] = bf2f(S0[base + (long long)(rb+i)*1024 + cb+tx]);
    t1 [i][tx] = bf2f(S1[base + (long long)(rb+i)*1024 + cb+tx]);
    t0t[i][tx] = bf2f(S0[base + (long long)(cb+i)*1024 + rb+tx]);
    t1t[i][tx] = bf2f(S1[base + (long long)(cb+i)*1024 + rb+tx]);
  }
  __syncthreads();
  #pragma unroll 1
  for (int rr=0;rr<2;rr++){
    const int i0 = ty + rr*16, i1 = i0 + 8;
    f32x2 s0, s1v, s0t, s1t, cr, cl;
    s0[0]  = t0 [i0][tx]; s0[1]  = t0 [i1][tx];
    s1v[0] = t1 [i0][tx]; s1v[1] = t1 [i1][tx];
    s0t[0] = t0t[tx][i0]; s0t[1] = t0t[tx][i1];
    s1t[0] = t1t[tx][i0]; s1t[1] = t1t[tx][i1];
    long long off0 = base + (long long)(rb+i0)*1024 + cb+tx;
    long long off1 = base + (long long)(rb+i1)*1024 + cb+tx;
    cr[0] = bf2f(CR[off0]); cr[1] = bf2f(CR[off1]);
    cl[0] = bf2f(CL[off0]); cl[1] = bf2f(CL[off1]);
    f32x2 a0 = bc(b2[0]), a1 = bc(b2[1]), a2 = bc(b2[2]), a3 = bc(b2[3]);
    #pragma unroll 4
    for (int o=0;o<16;o++){
      f32x2 xx = pkfma(bc(w1[o*6+0]), s0,  bc(b1[o]));
      xx = pkfma(bc(w1[o*6+1]), s1v, xx);
      xx = pkfma(bc(w1[o*6+2]), s0t, xx);
      xx = pkfma(bc(w1[o*6+3]), s1t, xx);
      xx = pkfma(bc(w1[o*6+4]), cr,  xx);
      xx = pkfma(bc(w1[o*6+5]), cl,  xx);
      f32x2 xx2 = xx*xx;
      f32x2 u   = pkfma(bc(0.044715f), xx2, bc(1.f));
      f32x2 zz  = (xx*u) * bc(1.5957691f);
      zz = pkmin(pkmax(zz, bc(-3.f)), bc(3.f));
      f32x2 w   = pkfma(bc(-0.011008f), zz*zz, bc(0.25f));
      f32x2 p   = pkfma(zz, w, bc(0.5f));
      f32x2 hh  = xx*p;
      a0 = pkfma(bc(w2[o]),    hh, a0);
      a1 = pkfma(bc(w2[16+o]), hh, a1);
      a2 = pkfma(bc(w2[32+o]), hh, a2);
      a3 = pkfma(bc(w2[48+o]), hh, a3);
    }
    f32x2 g0, g1, g2, g3;
    { float E;
      E=__expf(a0[0]); g0[0]=E*(1.f-E);  E=__expf(a0[1]); g0[1]=E*(1.f-E);
      E=__expf(a1[0]); g1[0]=E*(1.f-E);  E=__expf(a1[1]); g1[1]=E*(1.f-E);
      E=__expf(a2[0]); g2[0]=E*(1.f-E);  E=__expf(a2[1]); g2[1]=E*(1.f-E);
      E=__expf(a3[0]); g3[0]=E*(1.f-E);  E=__expf(a3[1]); g3[1]=E*(1.f-E);
    }
    f32x2 mx = pkmax(s0, s1v);
    f32x2 dd = s0 - s1v;
    f32x2 ad = pkmax(dd, bc(0.f)-dd);
    f32x2 ee, lg;
    ee[0] = __expf(-ad[0]); ee[1] = __expf(-ad[1]);
    lg[0] = __logf(1.f+ee[0]); lg[1] = __logf(1.f+ee[1]);
    f32x2 lse = mx + lg;
    f32x2 smix = s0 + g0*s1v + g1*(lse - s0) - g2*(bc(0.5f)*s1v) + g3*cr;
    Smix[off0] = f2bf(smix[0]);
    Smix[off1] = f2bf(smix[1]);
  }
}

extern "C" void kernel_launch(void* const* d_in, const int* in_sizes, int n_in,
                              void* d_out, int out_size, void* d_ws, size_t ws_size,
                              hipStream_t stream)
{
  const float* x     = (const float*)d_in[0];
  const float* Wqkv0 = (const float*)d_in[1];
  const float* Wqkv1 = (const float*)d_in[2];
  const float* Wproj = (const float*)d_in[3];
  const float* c1w   = (const float*)d_in[4];
  const float* c1b   = (const float*)d_in[5];
  const float* c2w   = (const float*)d_in[6];
  const float* c2b   = (const float*)d_in[7];
  const float* logit = (const float*)d_in[8];

  char* ws = (char*)d_ws;
  size_t off = 0;
  auto alloc = [&](size_t bytes)->char*{ char* p = ws + off; off = (off + bytes + 255) & ~(size_t)255; return p; };

  const long long NN16 = 16LL*1024*1024;
  u16* xb  = (u16*)alloc(2048LL*512*2);
  u16* w0T = (u16*)alloc(1536LL*512*2);
  u16* w1T = (u16*)alloc(1536LL*512*2);
  u16* wpT = (u16*)alloc(512LL*512*2);
  u16* q0  = (u16*)alloc(16LL*1024*64*2);
  u16* k0  = (u16*)alloc(16LL*1024*64*2);
  u16* v0T = (u16*)alloc(16LL*1024*64*2);
  u16* q1  = (u16*)alloc(16LL*1024*64*2);
  u16* k1  = (u16*)alloc(16LL*1024*64*2);
  u16* v1T = (u16*)alloc(16LL*1024*64*2);
  u16* S0b = (u16*)alloc(NN16*2);   // reused as Ab after gating
  u16* S1b = (u16*)alloc(NN16*2);
  u16* A0  = (u16*)alloc(NN16*2);
  u16* A1  = (u16*)alloc(NN16*2);
  u16* A0T = (u16*)alloc(NN16*2);   // reused as CR after CL GEMM
  u16* A1T = (u16*)alloc(NN16*2);   // reused as Smix after CR GEMM
  u16* CL  = (u16*)alloc(NN16*2);
  u16* tT  = (u16*)alloc(16LL*64*1024*2);
  u16* Yb  = (u16*)alloc(2048LL*512*2);

  u16* CR   = A0T;
  u16* Smix = A1T;
  u16* Ab   = S0b;

  if (off > ws_size){
    fprintf(stderr, "kernel_launch: ws too small: need %zu have %zu\n", off, ws_size);
    return;
  }

  dim3 blk(256);

  // 1. casts (x; w0T|w1T merged; wpT)
  cast_f32_bf16<<<dim3(262144/256), blk, 0, stream>>>(x, xb, 262144);
  castT_f32_bf16_2<<<dim3(48,16,2), blk, 0, stream>>>(Wqkv0, w0T, Wqkv1, w1T, 512, 1536);
  castT_f32_bf16<<<dim3(16,16), blk, 0, stream>>>(Wproj, wpT, 512, 512);

  // 2. QKV projections, both weight sets in one dispatch (z=0/1)
  gemm_bt<128,128,2,2,EPI_QKV,1><<<dim3(12,16,2), blk, 0, stream>>>(
      xb, w0T, xb, w1T, q0, k0, v0T, q1, k1, v1T, nullptr,
      512, 512, 512, 0, 0, 0, 0, 1);

  // 3. S0|S1 in one dispatch (z<16: S0, z>=16: S1)
  gemm_bt<128,128,2,2,EPI_BF16,1><<<dim3(8,8,32), blk, 0, stream>>>(
      q0, k0, q1, k1, S0b, nullptr, nullptr, S1b, nullptr, nullptr, nullptr,
      64, 64, 64, 65536, 65536, 1048576, 1024, 16);

  // 4+5. fused softmax+transpose: S0->A0,A0T ; S1->A1,A1T
  softmaxT<<<dim3(32,32), blk, 0, stream>>>(S0b, A0, A0T, S1b, A1, A1T);

  // 6. Cli then Cri (sequential: CR output aliases A0T which CL reads)
  gemm_bt<128,128,2,2,EPI_LOGBF16,0><<<dim3(8,8,16), blk, 0, stream>>>(
      A1, A0T, nullptr, nullptr, CL, nullptr, nullptr, nullptr, nullptr, nullptr, nullptr,
      1024, 1024, 1024, 1048576, 1048576, 1048576, 1024, 0);
  gemm_bt<128,128,2,2,EPI_LOGBF16,0><<<dim3(8,8,16), blk, 0, stream>>>(
      A0, A1T, nullptr, nullptr, CR, nullptr, nullptr, nullptr, nullptr, nullptr, nullptr,
      1024, 1024, 1024, 1048576, 1048576, 1048576, 1024, 0);

  // 7. gating -> Smix
  gating_kernel<<<dim3(32,32,16), blk, 0, stream>>>(S0b, S1b, CR, CL, c1w, c1b, c2w, c2b, Smix);

  // 8. A = softmax(Smix)
  softmax_rows2<<<dim3(16384), blk, 0, stream>>>(Smix, Ab, Smix, Ab, 16384);

  // 9. tT = ys * (A1 @ v1), transposed store (ys folded here)
  gemm_bt<64,64,2,2,EPI_BF16T,0><<<dim3(1,16,16), blk, 0, stream>>>(
      A1, v1T, nullptr, nullptr, tT, nullptr, nullptr, nullptr, nullptr, nullptr, logit,
      1024, 1024, 1024, 1048576, 65536, 65536, 1024, 0);

  // 10. Yb = Ab@v0T + A0@tT (dual-K, one epilogue, no RMW)
  gemm_bt<64,64,2,2,EPI_Y,2><<<dim3(1,16,16), blk, 0, stream>>>(
      Ab, v0T, A0, tT, Yb, nullptr, nullptr, nullptr, nullptr, nullptr, nullptr,
      1024, 1024, 1024, 1048576, 65536, 0, 0, 0);

  // 11. out = Y @ Wproj
  gemm_bt<64,64,2,2,EPI_F32,0><<<dim3(8,32,1), blk, 0, stream>>>(
      Yb, wpT, nullptr, nullptr, d_out, nullptr, nullptr, nullptr, nullptr, nullptr, nullptr,
      512, 512, 512, 0, 0, 0, 512, 0);

  (void)in_sizes; (void)n_in; (void)out_size;
}

// Round 20
// 371.444 us; speedup vs baseline: 1.2105x; 1.0310x over previous
//
#include <hip/hip_runtime.h>
#include <math.h>
#include <stdio.h>

// EdgewiseMSA: B=2, N=1024, DIM=512, H=8, DK=64, HIDDEN=16
// R20: (1) reassociate y_chain = A0@(A1@v1) = C_fwd@v1: CL/CR GEMMs store RAW
// C (bf16), gating computes log(C+eps) inline (+4 logf/pair, and log-of-raw is
// MORE accurate than bf16-of-log), ys=sigmoid(logit) folded into v1's QKV
// epilogue write -> tT GEMM deleted, Yb = dual-K(Ab@v0T, C_fwd@v1T').
// (2) wave-per-row softmax for Smix (no LDS/barriers, 6-shuffle reduce).
// Rest identical to R19 (382.9us).

typedef unsigned short u16;
typedef __attribute__((ext_vector_type(8))) short short8;
typedef __attribute__((ext_vector_type(4))) short short4v;
typedef __attribute__((ext_vector_type(4))) float f32x4;
typedef __attribute__((ext_vector_type(2))) float f32x2;
typedef __attribute__((ext_vector_type(16))) float f32x16;

#define DEVI static __device__ __forceinline__

DEVI float bf2f(u16 u){ union{unsigned v; float f;} x; x.v = ((unsigned)u)<<16u; return x.f; }
DEVI u16 f2bf(float f){ union{float f; unsigned v;} x; x.f=f; unsigned r = x.v + 0x7FFFu + ((x.v>>16)&1u); return (u16)(r>>16); }

DEVI f32x2 bc(float s){ f32x2 r; r[0]=s; r[1]=s; return r; }
DEVI f32x2 pkfma(f32x2 a, f32x2 b, f32x2 c){ return __builtin_elementwise_fma(a,b,c); }
DEVI f32x2 pkmin(f32x2 a, f32x2 b){ return __builtin_elementwise_min(a,b); }
DEVI f32x2 pkmax(f32x2 a, f32x2 b){ return __builtin_elementwise_max(a,b); }

DEVI void gload_lds16(const u16* gptr, u16* lptr){
  __builtin_amdgcn_global_load_lds(
      (const __attribute__((address_space(1))) void*)gptr,
      (__attribute__((address_space(3))) void*)lptr,
      16, 0, 0);
}

enum { EPI_F32=0, EPI_BF16=1, EPI_QKV=4, EPI_Y=5 };
// MODE: 0 = single; 1 = z-split; 2 = dual-K (acc += A@B then += A2@B2).

template<int BM,int BN,int WR,int WC,int EPI,int MODE>
__global__ __launch_bounds__(256) void gemm_bt(
    const u16* __restrict__ A, const u16* __restrict__ B,
    const u16* __restrict__ A2, const u16* __restrict__ B2,
    void* __restrict__ p0, void* __restrict__ p1, void* __restrict__ p2,
    void* __restrict__ p0b, void* __restrict__ p1b, void* __restrict__ p2b,
    const float* __restrict__ logit,
    int K, int lda, int ldb,
    long long sA, long long sB, long long sC, int ldc, int zsplit)
{
  constexpr int WM = BM/WR, WN = BN/WC;
  constexpr int MB = WM/32, NB = WN/32;
  constexpr int BK = 64;
  __shared__ u16 As[BM][BK];
  __shared__ u16 Bs[BN][BK];
  const int z = blockIdx.z;
  const bool sec = (MODE==1) && (z >= zsplit);
  const int ze = sec ? z - zsplit : z;
  const u16* Ap = (sec ? A2 : A) + (long long)ze*sA;
  const u16* Bp = (sec ? B2 : B) + (long long)ze*sB;
  void* o0 = sec ? p0b : p0;
  void* o1 = sec ? p1b : p1;
  void* o2 = sec ? p2b : p2;
  const int r0 = blockIdx.y*BM, c0 = blockIdx.x*BN;
  const int tid = threadIdx.x;
  const int wave = tid>>6, lane = tid&63;
  const int wr = (wave/WC)*WM, wc = (wave%WC)*WN;
  const int lrow = lane&31;
  const int kby  = (lane>>5)*16;
  const int l8 = lane>>3, l7 = lane&7;
  const int scol = ((l7 ^ l8) * 8);

  f32x16 acc[MB][NB] = {};

  auto kloop = [&](const u16* AP, const u16* BP){
    for (int k0=0; k0<K; k0+=BK){
      __syncthreads();
      #pragma unroll
      for (int i=0;i<BM/32;i++){
        int ins = wave + 4*i;
        int row = ins*8 + l8;
        gload_lds16(&AP[(long long)(r0+row)*lda + k0 + scol], &As[ins*8][0]);
      }
      #pragma unroll
      for (int i=0;i<BN/32;i++){
        int ins = wave + 4*i;
        int row = ins*8 + l8;
        gload_lds16(&BP[(long long)(c0+row)*ldb + k0 + scol], &Bs[ins*8][0]);
      }
      __syncthreads();
      #pragma unroll
      for (int kk=0; kk<4; ++kk){
        short8 af[MB], bfr[NB];
        #pragma unroll
        for (int m=0;m<MB;m++){
          int R = wr + m*32 + lrow;
          int eo = ((kk*32 + kby) ^ ((R&7)<<4)) >> 1;
          af[m] = *(const short8*)&As[R][eo];
        }
        #pragma unroll
        for (int n=0;n<NB;n++){
          int R = wc + n*32 + lrow;
          int eo = ((kk*32 + kby) ^ ((R&7)<<4)) >> 1;
          bfr[n] = *(const short8*)&Bs[R][eo];
        }
        #pragma unroll
        for (int m=0;m<MB;m++)
          #pragma unroll
          for (int n=0;n<NB;n++)
            acc[m][n] = __builtin_amdgcn_mfma_f32_32x32x16_bf16(af[m], bfr[n], acc[m][n], 0,0,0);
      }
    }
  };

  kloop(Ap, Bp);
  if constexpr (MODE==2){
    kloop(A2 + (long long)z*sA, B2 + (long long)z*sB);
  }

  float vscale = 1.f;
  if constexpr (EPI==EPI_QKV){ if (logit && sec) vscale = 1.f/(1.f+expf(-logit[0])); }

  #pragma unroll
  for (int m=0;m<MB;m++)
   #pragma unroll
   for (int n=0;n<NB;n++)
    #pragma unroll
    for (int reg=0;reg<16;reg++){
      int r = r0 + wr + m*32 + (reg&3) + 8*(reg>>2) + 4*(lane>>5);
      int c = c0 + wc + n*32 + lrow;
      float v = acc[m][n][reg];
      if constexpr (EPI==EPI_F32){
        ((float*)o0)[(long long)z*sC + (long long)r*ldc + c] = v;
      } else if constexpr (EPI==EPI_BF16){
        ((u16*)o0)[(long long)ze*sC + (long long)r*ldc + c] = f2bf(v);
      } else if constexpr (EPI==EPI_QKV){
        int b = r>>10, n_ = r&1023;
        int which = c>>9, h = (c>>6)&7, d = c&63;
        long long bh = (long long)b*8 + h;
        if (which==0)      ((u16*)o0)[(bh*1024 + n_)*64 + d] = f2bf(v*0.125f);
        else if (which==1) ((u16*)o1)[(bh*1024 + n_)*64 + d] = f2bf(v);
        else               ((u16*)o2)[(bh*64 + d)*1024 + n_] = f2bf(v*vscale);
      } else if constexpr (EPI==EPI_Y){
        int b = z>>3, h = z&7;
        ((u16*)o0)[((long long)(b*1024 + r))*512 + h*64 + c] = f2bf(v);
      }
    }
}

// fused row-softmax + transpose: reads S (32 rows/block), writes A and A^T.
__global__ __launch_bounds__(256) void softmaxT(
    const u16* __restrict__ Sa, u16* __restrict__ Aa, u16* __restrict__ ATa,
    const u16* __restrict__ Sb, u16* __restrict__ Ab2, u16* __restrict__ ATb)
{
  __shared__ u16 tile[32][1032];
  const int zz = blockIdx.y;
  const long long nn = 1048576;
  const u16* S; u16 *A; u16 *AT;
  if (zz < 16){ S = Sa + (long long)zz*nn;      A = Aa  + (long long)zz*nn;      AT = ATa + (long long)zz*nn; }
  else        { S = Sb + (long long)(zz-16)*nn; A = Ab2 + (long long)(zz-16)*nn; AT = ATb + (long long)(zz-16)*nn; }
  const int rb = blockIdx.x*32;
  const int tid = threadIdx.x;

  #pragma unroll
  for (int i=0;i<16;i++){
    int f = tid + i*256;
    int r = f>>7, c = (f&127)*8;
    *(short8*)&tile[r][c] = *(const short8*)&S[(long long)(rb+r)*1024 + c];
  }
  __syncthreads();

  const int row = ((tid>>6)<<3) + ((tid&63)>>3);
  const int seg = tid&7;
  float m = -3.4e38f;
  #pragma unroll
  for (int j=0;j<16;j++){
    short8 x = *(const short8*)&tile[row][seg*128 + j*8];
    #pragma unroll
    for (int q=0;q<8;q++) m = fmaxf(m, bf2f((u16)x[q]));
  }
  m = fmaxf(m, __shfl_xor(m,1,64));
  m = fmaxf(m, __shfl_xor(m,2,64));
  m = fmaxf(m, __shfl_xor(m,4,64));
  float s = 0.f;
  #pragma unroll
  for (int j=0;j<16;j++){
    short8 x = *(const short8*)&tile[row][seg*128 + j*8];
    #pragma unroll
    for (int q=0;q<8;q++) s += __expf(bf2f((u16)x[q]) - m);
  }
  s += __shfl_xor(s,1,64);
  s += __shfl_xor(s,2,64);
  s += __shfl_xor(s,4,64);
  float inv = 1.f/s;
  #pragma unroll
  for (int j=0;j<16;j++){
    short8 x = *(const short8*)&tile[row][seg*128 + j*8];
    short8 o;
    #pragma unroll
    for (int q=0;q<8;q++) o[q] = (short)f2bf(__expf(bf2f((u16)x[q]) - m)*inv);
    *(short8*)&tile[row][seg*128 + j*8] = o;
  }
  __syncthreads();
  #pragma unroll
  for (int i=0;i<16;i++){
    int f = tid + i*256;
    int r = f>>7, c = (f&127)*8;
    *(short8*)&A[(long long)(rb+r)*1024 + c] = *(const short8*)&tile[r][c];
  }
  #pragma unroll
  for (int i=0;i<4;i++){
    int c = tid*4 + i;
    short8 o0, o1, o2, o3;
    #pragma unroll
    for (int q=0;q<8;q++){
      o0[q] = (short)tile[q][c];
      o1[q] = (short)tile[8+q][c];
      o2[q] = (short)tile[16+q][c];
      o3[q] = (short)tile[24+q][c];
    }
    u16* dst = &AT[(long long)c*1024 + rb];
    *(short8*)&dst[0]  = o0;
    *(short8*)&dst[8]  = o1;
    *(short8*)&dst[16] = o2;
    *(short8*)&dst[24] = o3;
  }
}

// wave-per-row softmax: 4 rows/block, no LDS/barriers; 16 elem/lane.
__global__ __launch_bounds__(256) void softmax_wave(
    const u16* __restrict__ S, u16* __restrict__ A)
{
  const int wave = threadIdx.x>>6, lane = threadIdx.x&63;
  const long long row = (long long)blockIdx.x*4 + wave;
  const u16* s = S + row*1024;
  u16* a = A + row*1024;
  short8 x0 = *(const short8*)&s[lane*16];
  short8 x1 = *(const short8*)&s[lane*16+8];
  float v[16];
  #pragma unroll
  for (int q=0;q<8;q++){ v[q]=bf2f((u16)x0[q]); v[8+q]=bf2f((u16)x1[q]); }
  float m = v[0];
  #pragma unroll
  for (int q=1;q<16;q++) m = fmaxf(m, v[q]);
  #pragma unroll
  for (int off=32; off>0; off>>=1) m = fmaxf(m, __shfl_xor(m, off, 64));
  float sum = 0.f;
  #pragma unroll
  for (int q=0;q<16;q++){ v[q] = __expf(v[q]-m); sum += v[q]; }
  #pragma unroll
  for (int off=32; off>0; off>>=1) sum += __shfl_xor(sum, off, 64);
  float inv = 1.f/sum;
  short8 o0, o1;
  #pragma unroll
  for (int q=0;q<8;q++){ o0[q]=(short)f2bf(v[q]*inv); o1[q]=(short)f2bf(v[8+q]*inv); }
  *(short8*)&a[lane*16]   = o0;
  *(short8*)&a[lane*16+8] = o1;
}

__global__ __launch_bounds__(256) void cast_f32_bf16(const float* __restrict__ in, u16* __restrict__ out, int n4)
{
  int i = blockIdx.x*256 + threadIdx.x;
  if (i < n4){
    f32x4 x = ((const f32x4*)in)[i];
    short4v o;
    #pragma unroll
    for (int j=0;j<4;j++) o[j] = (short)f2bf(x[j]);
    ((short4v*)out)[i] = o;
  }
}

__global__ __launch_bounds__(256) void castT_f32_bf16_2(
    const float* __restrict__ in0, u16* __restrict__ out0,
    const float* __restrict__ in1, u16* __restrict__ out1, int rows, int cols)
{
  __shared__ float tile[32][33];
  const float* in = blockIdx.z ? in1 : in0;
  u16* out        = blockIdx.z ? out1 : out0;
  const int cb = blockIdx.x*32, rb = blockIdx.y*32;
  const int tx = threadIdx.x&31, ty = threadIdx.x>>5;
  #pragma unroll
  for (int rr=0;rr<4;rr++){
    int i = ty + rr*8;
    tile[i][tx] = in[(long long)(rb+i)*cols + cb+tx];
  }
  __syncthreads();
  #pragma unroll
  for (int rr=0;rr<4;rr++){
    int i = ty + rr*8;
    out[(long long)(cb+i)*rows + rb+tx] = f2bf(tile[tx][i]);
  }
}

__global__ __launch_bounds__(256) void castT_f32_bf16(const float* __restrict__ in, u16* __restrict__ out, int rows, int cols)
{
  __shared__ float tile[32][33];
  const int cb = blockIdx.x*32, rb = blockIdx.y*32;
  const int tx = threadIdx.x&31, ty = threadIdx.x>>5;
  #pragma unroll
  for (int rr=0;rr<4;rr++){
    int i = ty + rr*8;
    tile[i][tx] = in[(long long)(rb+i)*cols + cb+tx];
  }
  __syncthreads();
  #pragma unroll
  for (int rr=0;rr<4;rr++){
    int i = ty + rr*8;
    out[(long long)(cb+i)*rows + rb+tx] = f2bf(tile[tx][i]);
  }
}

// gating + Smix -> Smix bf16 (R13 structure). CR/CL now RAW C values:
// cr = log(CR+eps), cl = log(CL+eps) computed inline.
__global__ __launch_bounds__(256) void gating_kernel(
    const u16* __restrict__ S0, const u16* __restrict__ S1,
    const u16* __restrict__ CR, const u16* __restrict__ CL,
    const float* __restrict__ w1, const float* __restrict__ b1,
    const float* __restrict__ w2, const float* __restrict__ b2,
    u16* __restrict__ Smix)
{
  __shared__ float t0[32][33], t1[32][33], t0t[32][33], t1t[32][33];
  const int tid = threadIdx.x;
  const long long base = (long long)blockIdx.z*1024*1024;
  const int rb = blockIdx.y*32, cb = blockIdx.x*32;
  const int tx = tid&31, ty = tid>>5;
  #pragma unroll
  for (int rr=0;rr<4;rr++){
    int i = ty + rr*8;
    t0 [i][tx] = bf2f(S0[base + (long long)(rb+i)*1024 + cb+tx]);
    t1 [i][tx] = bf2f(S1[base + (long long)(rb+i)*1024 + cb+tx]);
    t0t[i][tx] = bf2f(S0[base + (long long)(cb+i)*1024 + rb+tx]);
    t1t[i][tx] = bf2f(S1[base + (long long)(cb+i)*1024 + rb+tx]);
  }
  __syncthreads();
  #pragma unroll 1
  for (int rr=0;rr<2;rr++){
    const int i0 = ty + rr*16, i1 = i0 + 8;
    f32x2 s0, s1v, s0t, s1t, cr, cl;
    s0[0]  = t0 [i0][tx]; s0[1]  = t0 [i1][tx];
    s1v[0] = t1 [i0][tx]; s1v[1] = t1 [i1][tx];
    s0t[0] = t0t[tx][i0]; s0t[1] = t0t[tx][i1];
    s1t[0] = t1t[tx][i0]; s1t[1] = t1t[tx][i1];
    long long off0 = base + (long long)(rb+i0)*1024 + cb+tx;
    long long off1 = base + (long long)(rb+i1)*1024 + cb+tx;
    cr[0] = __logf(bf2f(CR[off0]) + 1e-6f); cr[1] = __logf(bf2f(CR[off1]) + 1e-6f);
    cl[0] = __logf(bf2f(CL[off0]) + 1e-6f); cl[1] = __logf(bf2f(CL[off1]) + 1e-6f);
    f32x2 a0 = bc(b2[0]), a1 = bc(b2[1]), a2 = bc(b2[2]), a3 = bc(b2[3]);
    #pragma unroll 4
    for (int o=0;o<16;o++){
      f32x2 xx = pkfma(bc(w1[o*6+0]), s0,  bc(b1[o]));
      xx = pkfma(bc(w1[o*6+1]), s1v, xx);
      xx = pkfma(bc(w1[o*6+2]), s0t, xx);
      xx = pkfma(bc(w1[o*6+3]), s1t, xx);
      xx = pkfma(bc(w1[o*6+4]), cr,  xx);
      xx = pkfma(bc(w1[o*6+5]), cl,  xx);
      f32x2 xx2 = xx*xx;
      f32x2 u   = pkfma(bc(0.044715f), xx2, bc(1.f));
      f32x2 zz  = (xx*u) * bc(1.5957691f);
      zz = pkmin(pkmax(zz, bc(-3.f)), bc(3.f));
      f32x2 w   = pkfma(bc(-0.011008f), zz*zz, bc(0.25f));
      f32x2 p   = pkfma(zz, w, bc(0.5f));
      f32x2 hh  = xx*p;
      a0 = pkfma(bc(w2[o]),    hh, a0);
      a1 = pkfma(bc(w2[16+o]), hh, a1);
      a2 = pkfma(bc(w2[32+o]), hh, a2);
      a3 = pkfma(bc(w2[48+o]), hh, a3);
    }
    f32x2 g0, g1, g2, g3;
    { float E;
      E=__expf(a0[0]); g0[0]=E*(1.f-E);  E=__expf(a0[1]); g0[1]=E*(1.f-E);
      E=__expf(a1[0]); g1[0]=E*(1.f-E);  E=__expf(a1[1]); g1[1]=E*(1.f-E);
      E=__expf(a2[0]); g2[0]=E*(1.f-E);  E=__expf(a2[1]); g2[1]=E*(1.f-E);
      E=__expf(a3[0]); g3[0]=E*(1.f-E);  E=__expf(a3[1]); g3[1]=E*(1.f-E);
    }
    f32x2 mx = pkmax(s0, s1v);
    f32x2 dd = s0 - s1v;
    f32x2 ad = pkmax(dd, bc(0.f)-dd);
    f32x2 ee, lg;
    ee[0] = __expf(-ad[0]); ee[1] = __expf(-ad[1]);
    lg[0] = __logf(1.f+ee[0]); lg[1] = __logf(1.f+ee[1]);
    f32x2 lse = mx + lg;
    f32x2 smix = s0 + g0*s1v + g1*(lse - s0) - g2*(bc(0.5f)*s1v) + g3*cr;
    Smix[off0] = f2bf(smix[0]);
    Smix[off1] = f2bf(smix[1]);
  }
}

extern "C" void kernel_launch(void* const* d_in, const int* in_sizes, int n_in,
                              void* d_out, int out_size, void* d_ws, size_t ws_size,
                              hipStream_t stream)
{
  const float* x     = (const float*)d_in[0];
  const float* Wqkv0 = (const float*)d_in[1];
  const float* Wqkv1 = (const float*)d_in[2];
  const float* Wproj = (const float*)d_in[3];
  const float* c1w   = (const float*)d_in[4];
  const float* c1b   = (const float*)d_in[5];
  const float* c2w   = (const float*)d_in[6];
  const float* c2b   = (const float*)d_in[7];
  const float* logit = (const float*)d_in[8];

  char* ws = (char*)d_ws;
  size_t off = 0;
  auto alloc = [&](size_t bytes)->char*{ char* p = ws + off; off = (off + bytes + 255) & ~(size_t)255; return p; };

  const long long NN16 = 16LL*1024*1024;
  u16* xb  = (u16*)alloc(2048LL*512*2);
  u16* w0T = (u16*)alloc(1536LL*512*2);
  u16* w1T = (u16*)alloc(1536LL*512*2);
  u16* wpT = (u16*)alloc(512LL*512*2);
  u16* q0  = (u16*)alloc(16LL*1024*64*2);
  u16* k0  = (u16*)alloc(16LL*1024*64*2);
  u16* v0T = (u16*)alloc(16LL*1024*64*2);
  u16* q1  = (u16*)alloc(16LL*1024*64*2);
  u16* k1  = (u16*)alloc(16LL*1024*64*2);
  u16* v1T = (u16*)alloc(16LL*1024*64*2);  // pre-scaled by ys in QKV epilogue
  u16* S0b = (u16*)alloc(NN16*2);   // reused as Ab after gating
  u16* S1b = (u16*)alloc(NN16*2);
  u16* A0  = (u16*)alloc(NN16*2);
  u16* A1  = (u16*)alloc(NN16*2);
  u16* A0T = (u16*)alloc(NN16*2);   // reused as CR (raw C_fwd) after CL GEMM
  u16* A1T = (u16*)alloc(NN16*2);   // reused as Smix after CR GEMM
  u16* CL  = (u16*)alloc(NN16*2);   // raw C_bwd
  u16* Yb  = (u16*)alloc(2048LL*512*2);

  u16* CR   = A0T;
  u16* Smix = A1T;
  u16* Ab   = S0b;

  if (off > ws_size){
    fprintf(stderr, "kernel_launch: ws too small: need %zu have %zu\n", off, ws_size);
    return;
  }

  dim3 blk(256);

  // 1. casts (x; w0T|w1T merged; wpT)
  cast_f32_bf16<<<dim3(262144/256), blk, 0, stream>>>(x, xb, 262144);
  castT_f32_bf16_2<<<dim3(48,16,2), blk, 0, stream>>>(Wqkv0, w0T, Wqkv1, w1T, 512, 1536);
  castT_f32_bf16<<<dim3(16,16), blk, 0, stream>>>(Wproj, wpT, 512, 512);

  // 2. QKV projections; v1 writes pre-scaled by ys=sigmoid(logit) (sec half)
  gemm_bt<128,128,2,2,EPI_QKV,1><<<dim3(12,16,2), blk, 0, stream>>>(
      xb, w0T, xb, w1T, q0, k0, v0T, q1, k1, v1T, logit,
      512, 512, 512, 0, 0, 0, 0, 1);

  // 3. S0|S1 in one dispatch
  gemm_bt<128,128,2,2,EPI_BF16,1><<<dim3(8,8,32), blk, 0, stream>>>(
      q0, k0, q1, k1, S0b, nullptr, nullptr, S1b, nullptr, nullptr, nullptr,
      64, 64, 64, 65536, 65536, 1048576, 1024, 16);

  // 4. fused softmax+transpose: S0->A0,A0T ; S1->A1,A1T
  softmaxT<<<dim3(32,32), blk, 0, stream>>>(S0b, A0, A0T, S1b, A1, A1T);

  // 5. raw C_bwd = A1@A0 (into CL), then raw C_fwd = A0@A1 (into CR=A0T space)
  gemm_bt<128,128,2,2,EPI_BF16,0><<<dim3(8,8,16), blk, 0, stream>>>(
      A1, A0T, nullptr, nullptr, CL, nullptr, nullptr, nullptr, nullptr, nullptr, nullptr,
      1024, 1024, 1024, 1048576, 1048576, 1048576, 1024, 0);
  gemm_bt<128,128,2,2,EPI_BF16,0><<<dim3(8,8,16), blk, 0, stream>>>(
      A0, A1T, nullptr, nullptr, CR, nullptr, nullptr, nullptr, nullptr, nullptr, nullptr,
      1024, 1024, 1024, 1048576, 1048576, 1048576, 1024, 0);

  // 6. gating -> Smix (log of raw C inline)
  gating_kernel<<<dim3(32,32,16), blk, 0, stream>>>(S0b, S1b, CR, CL, c1w, c1b, c2w, c2b, Smix);

  // 7. A = softmax(Smix), wave-per-row
  softmax_wave<<<dim3(4096), blk, 0, stream>>>(Smix, Ab);

  // 8. Yb = Ab@v0T + C_fwd@v1T' (dual-K; ys already folded into v1T)
  gemm_bt<64,64,2,2,EPI_Y,2><<<dim3(1,16,16), blk, 0, stream>>>(
      Ab, v0T, CR, v1T, Yb, nullptr, nullptr, nullptr, nullptr, nullptr, nullptr,
      1024, 1024, 1024, 1048576, 65536, 0, 0, 0);

  // 9. out = Y @ Wproj
  gemm_bt<64,64,2,2,EPI_F32,0><<<dim3(8,32,1), blk, 0, stream>>>(
      Yb, wpT, nullptr, nullptr, d_out, nullptr, nullptr, nullptr, nullptr, nullptr, nullptr,
      512, 512, 512, 0, 0, 0, 512, 0);

  (void)in_sizes; (void)n_in; (void)out_size;
}

// Round 22
// 370.071 us; speedup vs baseline: 1.2150x; 1.0037x over previous
//
#include <hip/hip_runtime.h>
#include <math.h>
#include <stdio.h>

// EdgewiseMSA: B=2, N=1024, DIM=512, H=8, DK=64, HIDDEN=16
// R22 = R21 with the call-site arity bug fixed (N7 macro gave 7 nullptrs for
// 6 trailing pointer slots; now explicit args everywhere).
// R21: (1) logs in C-GEMM epilogues: CL -> log-only; CR -> dual-write raw
// C_fwd + log C_fwd (dead A1 buffer). Gating uses direct log loads (129us
// form). (2) Yb GEMM split-K 4x512 -> 1024 blocks + 3us reduce (was 40us
// latency-bound at 256 blocks).

typedef unsigned short u16;
typedef __attribute__((ext_vector_type(8))) short short8;
typedef __attribute__((ext_vector_type(4))) short short4v;
typedef __attribute__((ext_vector_type(4))) float f32x4;
typedef __attribute__((ext_vector_type(2))) float f32x2;
typedef __attribute__((ext_vector_type(16))) float f32x16;

#define DEVI static __device__ __forceinline__

DEVI float bf2f(u16 u){ union{unsigned v; float f;} x; x.v = ((unsigned)u)<<16u; return x.f; }
DEVI u16 f2bf(float f){ union{float f; unsigned v;} x; x.f=f; unsigned r = x.v + 0x7FFFu + ((x.v>>16)&1u); return (u16)(r>>16); }

DEVI f32x2 bc(float s){ f32x2 r; r[0]=s; r[1]=s; return r; }
DEVI f32x2 pkfma(f32x2 a, f32x2 b, f32x2 c){ return __builtin_elementwise_fma(a,b,c); }
DEVI f32x2 pkmin(f32x2 a, f32x2 b){ return __builtin_elementwise_min(a,b); }
DEVI f32x2 pkmax(f32x2 a, f32x2 b){ return __builtin_elementwise_max(a,b); }

DEVI void gload_lds16(const u16* gptr, u16* lptr){
  __builtin_amdgcn_global_load_lds(
      (const __attribute__((address_space(1))) void*)gptr,
      (__attribute__((address_space(3))) void*)lptr,
      16, 0, 0);
}

enum { EPI_F32=0, EPI_BF16=1, EPI_LOGBF16=2, EPI_RAWLOG=3, EPI_QKV=4, EPI_PF32=5 };
// MODE: 0 = single; 1 = z-split; 3 = split-K (z = tile*4 + s; s<2: A/B chunk s,
//       s>=2: A2/B2 chunk s-2; kb = (s&1)*512; f32 partial out).

template<int BM,int BN,int WR,int WC,int EPI,int MODE>
__global__ __launch_bounds__(256) void gemm_bt(
    const u16* __restrict__ A, const u16* __restrict__ B,
    const u16* __restrict__ A2, const u16* __restrict__ B2,
    void* __restrict__ p0, void* __restrict__ p1, void* __restrict__ p2,
    void* __restrict__ p0b, void* __restrict__ p1b, void* __restrict__ p2b,
    const float* __restrict__ logit,
    int K, int lda, int ldb,
    long long sA, long long sB, long long sC, int ldc, int zsplit)
{
  constexpr int WM = BM/WR, WN = BN/WC;
  constexpr int MB = WM/32, NB = WN/32;
  constexpr int BK = 64;
  __shared__ u16 As[BM][BK];
  __shared__ u16 Bs[BN][BK];
  const int z = blockIdx.z;
  int ze = z, kb = 0;
  bool sec = false;
  const u16 *Ap, *Bp;
  void *o0 = p0, *o1 = p1, *o2 = p2;
  if constexpr (MODE==1){
    sec = (z >= zsplit); ze = sec ? z - zsplit : z;
    Ap = (sec ? A2 : A) + (long long)ze*sA;
    Bp = (sec ? B2 : B) + (long long)ze*sB;
    if (sec){ o0 = p0b; o1 = p1b; o2 = p2b; }
  } else if constexpr (MODE==3){
    int s = z & 3; ze = z >> 2; kb = (s&1)*512;
    Ap = (s<2 ? A : A2) + (long long)ze*sA;
    Bp = (s<2 ? B : B2) + (long long)ze*sB;
  } else {
    Ap = A + (long long)z*sA;
    Bp = B + (long long)z*sB;
  }
  const int r0 = blockIdx.y*BM, c0 = blockIdx.x*BN;
  const int tid = threadIdx.x;
  const int wave = tid>>6, lane = tid&63;
  const int wr = (wave/WC)*WM, wc = (wave%WC)*WN;
  const int lrow = lane&31;
  const int kby  = (lane>>5)*16;
  const int l8 = lane>>3, l7 = lane&7;
  const int scol = ((l7 ^ l8) * 8);

  f32x16 acc[MB][NB] = {};

  for (int k0=kb; k0<kb+K; k0+=BK){
    __syncthreads();
    #pragma unroll
    for (int i=0;i<BM/32;i++){
      int ins = wave + 4*i;
      int row = ins*8 + l8;
      gload_lds16(&Ap[(long long)(r0+row)*lda + k0 + scol], &As[ins*8][0]);
    }
    #pragma unroll
    for (int i=0;i<BN/32;i++){
      int ins = wave + 4*i;
      int row = ins*8 + l8;
      gload_lds16(&Bp[(long long)(c0+row)*ldb + k0 + scol], &Bs[ins*8][0]);
    }
    __syncthreads();
    #pragma unroll
    for (int kk=0; kk<4; ++kk){
      short8 af[MB], bfr[NB];
      #pragma unroll
      for (int m=0;m<MB;m++){
        int R = wr + m*32 + lrow;
        int eo = ((kk*32 + kby) ^ ((R&7)<<4)) >> 1;
        af[m] = *(const short8*)&As[R][eo];
      }
      #pragma unroll
      for (int n=0;n<NB;n++){
        int R = wc + n*32 + lrow;
        int eo = ((kk*32 + kby) ^ ((R&7)<<4)) >> 1;
        bfr[n] = *(const short8*)&Bs[R][eo];
      }
      #pragma unroll
      for (int m=0;m<MB;m++)
        #pragma unroll
        for (int n=0;n<NB;n++)
          acc[m][n] = __builtin_amdgcn_mfma_f32_32x32x16_bf16(af[m], bfr[n], acc[m][n], 0,0,0);
    }
  }

  float vscale = 1.f;
  if constexpr (EPI==EPI_QKV){ if (logit && sec) vscale = 1.f/(1.f+expf(-logit[0])); }

  #pragma unroll
  for (int m=0;m<MB;m++)
   #pragma unroll
   for (int n=0;n<NB;n++)
    #pragma unroll
    for (int reg=0;reg<16;reg++){
      int r = r0 + wr + m*32 + (reg&3) + 8*(reg>>2) + 4*(lane>>5);
      int c = c0 + wc + n*32 + lrow;
      float v = acc[m][n][reg];
      if constexpr (EPI==EPI_F32){
        ((float*)o0)[(long long)z*sC + (long long)r*ldc + c] = v;
      } else if constexpr (EPI==EPI_BF16){
        ((u16*)o0)[(long long)ze*sC + (long long)r*ldc + c] = f2bf(v);
      } else if constexpr (EPI==EPI_LOGBF16){
        ((u16*)o0)[(long long)z*sC + (long long)r*ldc + c] = f2bf(__logf(v + 1e-6f));
      } else if constexpr (EPI==EPI_RAWLOG){
        long long off = (long long)z*sC + (long long)r*ldc + c;
        ((u16*)o0)[off] = f2bf(v);
        ((u16*)o1)[off] = f2bf(__logf(v + 1e-6f));
      } else if constexpr (EPI==EPI_QKV){
        int b = r>>10, n_ = r&1023;
        int which = c>>9, h = (c>>6)&7, d = c&63;
        long long bh = (long long)b*8 + h;
        if (which==0)      ((u16*)o0)[(bh*1024 + n_)*64 + d] = f2bf(v*0.125f);
        else if (which==1) ((u16*)o1)[(bh*1024 + n_)*64 + d] = f2bf(v);
        else               ((u16*)o2)[(bh*64 + d)*1024 + n_] = f2bf(v*vscale);
      } else if constexpr (EPI==EPI_PF32){
        int s = z & 3;
        ((float*)o0)[(long long)s*1048576 + (long long)ze*65536 + (long long)r*64 + c] = v;
      }
    }
}

// reduce 4 f32 split-K partials -> Yb bf16 with EPI_Y scatter layout
__global__ __launch_bounds__(256) void reduce4_yb(const float* __restrict__ P, u16* __restrict__ Yb)
{
  int i = (blockIdx.x*256 + threadIdx.x)*4;
  f32x4 a = *(const f32x4*)&P[i];
  f32x4 b = *(const f32x4*)&P[1048576 + i];
  f32x4 c = *(const f32x4*)&P[2097152 + i];
  f32x4 d = *(const f32x4*)&P[3145728 + i];
  int z = i>>16, r = (i>>6)&1023, cc = i&63;
  int bb = z>>3, h = z&7;
  long long o = ((long long)(bb*1024 + r))*512 + h*64 + cc;
  short4v out;
  #pragma unroll
  for (int q=0;q<4;q++) out[q] = (short)f2bf(a[q]+b[q]+c[q]+d[q]);
  *(short4v*)&Yb[o] = out;
}

// fused row-softmax + transpose: reads S (32 rows/block), writes A and A^T.
__global__ __launch_bounds__(256) void softmaxT(
    const u16* __restrict__ Sa, u16* __restrict__ Aa, u16* __restrict__ ATa,
    const u16* __restrict__ Sb, u16* __restrict__ Ab2, u16* __restrict__ ATb)
{
  __shared__ u16 tile[32][1032];
  const int zz = blockIdx.y;
  const long long nn = 1048576;
  const u16* S; u16 *A; u16 *AT;
  if (zz < 16){ S = Sa + (long long)zz*nn;      A = Aa  + (long long)zz*nn;      AT = ATa + (long long)zz*nn; }
  else        { S = Sb + (long long)(zz-16)*nn; A = Ab2 + (long long)(zz-16)*nn; AT = ATb + (long long)(zz-16)*nn; }
  const int rb = blockIdx.x*32;
  const int tid = threadIdx.x;

  #pragma unroll
  for (int i=0;i<16;i++){
    int f = tid + i*256;
    int r = f>>7, c = (f&127)*8;
    *(short8*)&tile[r][c] = *(const short8*)&S[(long long)(rb+r)*1024 + c];
  }
  __syncthreads();

  const int row = ((tid>>6)<<3) + ((tid&63)>>3);
  const int seg = tid&7;
  float m = -3.4e38f;
  #pragma unroll
  for (int j=0;j<16;j++){
    short8 x = *(const short8*)&tile[row][seg*128 + j*8];
    #pragma unroll
    for (int q=0;q<8;q++) m = fmaxf(m, bf2f((u16)x[q]));
  }
  m = fmaxf(m, __shfl_xor(m,1,64));
  m = fmaxf(m, __shfl_xor(m,2,64));
  m = fmaxf(m, __shfl_xor(m,4,64));
  float s = 0.f;
  #pragma unroll
  for (int j=0;j<16;j++){
    short8 x = *(const short8*)&tile[row][seg*128 + j*8];
    #pragma unroll
    for (int q=0;q<8;q++) s += __expf(bf2f((u16)x[q]) - m);
  }
  s += __shfl_xor(s,1,64);
  s += __shfl_xor(s,2,64);
  s += __shfl_xor(s,4,64);
  float inv = 1.f/s;
  #pragma unroll
  for (int j=0;j<16;j++){
    short8 x = *(const short8*)&tile[row][seg*128 + j*8];
    short8 o;
    #pragma unroll
    for (int q=0;q<8;q++) o[q] = (short)f2bf(__expf(bf2f((u16)x[q]) - m)*inv);
    *(short8*)&tile[row][seg*128 + j*8] = o;
  }
  __syncthreads();
  #pragma unroll
  for (int i=0;i<16;i++){
    int f = tid + i*256;
    int r = f>>7, c = (f&127)*8;
    *(short8*)&A[(long long)(rb+r)*1024 + c] = *(const short8*)&tile[r][c];
  }
  #pragma unroll
  for (int i=0;i<4;i++){
    int c = tid*4 + i;
    short8 o0, o1, o2, o3;
    #pragma unroll
    for (int q=0;q<8;q++){
      o0[q] = (short)tile[q][c];
      o1[q] = (short)tile[8+q][c];
      o2[q] = (short)tile[16+q][c];
      o3[q] = (short)tile[24+q][c];
    }
    u16* dst = &AT[(long long)c*1024 + rb];
    *(short8*)&dst[0]  = o0;
    *(short8*)&dst[8]  = o1;
    *(short8*)&dst[16] = o2;
    *(short8*)&dst[24] = o3;
  }
}

// wave-per-row softmax: 4 rows/block, no LDS/barriers; 16 elem/lane.
__global__ __launch_bounds__(256) void softmax_wave(
    const u16* __restrict__ S, u16* __restrict__ A)
{
  const int wave = threadIdx.x>>6, lane = threadIdx.x&63;
  const long long row = (long long)blockIdx.x*4 + wave;
  const u16* s = S + row*1024;
  u16* a = A + row*1024;
  short8 x0 = *(const short8*)&s[lane*16];
  short8 x1 = *(const short8*)&s[lane*16+8];
  float v[16];
  #pragma unroll
  for (int q=0;q<8;q++){ v[q]=bf2f((u16)x0[q]); v[8+q]=bf2f((u16)x1[q]); }
  float m = v[0];
  #pragma unroll
  for (int q=1;q<16;q++) m = fmaxf(m, v[q]);
  #pragma unroll
  for (int off=32; off>0; off>>=1) m = fmaxf(m, __shfl_xor(m, off, 64));
  float sum = 0.f;
  #pragma unroll
  for (int q=0;q<16;q++){ v[q] = __expf(v[q]-m); sum += v[q]; }
  #pragma unroll
  for (int off=32; off>0; off>>=1) sum += __shfl_xor(sum, off, 64);
  float inv = 1.f/sum;
  short8 o0, o1;
  #pragma unroll
  for (int q=0;q<8;q++){ o0[q]=(short)f2bf(v[q]*inv); o1[q]=(short)f2bf(v[8+q]*inv); }
  *(short8*)&a[lane*16]   = o0;
  *(short8*)&a[lane*16+8] = o1;
}

__global__ __launch_bounds__(256) void cast_f32_bf16(const float* __restrict__ in, u16* __restrict__ out, int n4)
{
  int i = blockIdx.x*256 + threadIdx.x;
  if (i < n4){
    f32x4 x = ((const f32x4*)in)[i];
    short4v o;
    #pragma unroll
    for (int j=0;j<4;j++) o[j] = (short)f2bf(x[j]);
    ((short4v*)out)[i] = o;
  }
}

__global__ __launch_bounds__(256) void castT_f32_bf16_2(
    const float* __restrict__ in0, u16* __restrict__ out0,
    const float* __restrict__ in1, u16* __restrict__ out1, int rows, int cols)
{
  __shared__ float tile[32][33];
  const float* in = blockIdx.z ? in1 : in0;
  u16* out        = blockIdx.z ? out1 : out0;
  const int cb = blockIdx.x*32, rb = blockIdx.y*32;
  const int tx = threadIdx.x&31, ty = threadIdx.x>>5;
  #pragma unroll
  for (int rr=0;rr<4;rr++){
    int i = ty + rr*8;
    tile[i][tx] = in[(long long)(rb+i)*cols + cb+tx];
  }
  __syncthreads();
  #pragma unroll
  for (int rr=0;rr<4;rr++){
    int i = ty + rr*8;
    out[(long long)(cb+i)*rows + rb+tx] = f2bf(tile[tx][i]);
  }
}

__global__ __launch_bounds__(256) void castT_f32_bf16(const float* __restrict__ in, u16* __restrict__ out, int rows, int cols)
{
  __shared__ float tile[32][33];
  const int cb = blockIdx.x*32, rb = blockIdx.y*32;
  const int tx = threadIdx.x&31, ty = threadIdx.x>>5;
  #pragma unroll
  for (int rr=0;rr<4;rr++){
    int i = ty + rr*8;
    tile[i][tx] = in[(long long)(rb+i)*cols + cb+tx];
  }
  __syncthreads();
  #pragma unroll
  for (int rr=0;rr<4;rr++){
    int i = ty + rr*8;
    out[(long long)(cb+i)*rows + rb+tx] = f2bf(tile[tx][i]);
  }
}

// gating + Smix -> Smix bf16 (R13 structure; CRl/CLl hold log values).
__global__ __launch_bounds__(256) void gating_kernel(
    const u16* __restrict__ S0, const u16* __restrict__ S1,
    const u16* __restrict__ CRl, const u16* __restrict__ CLl,
    const float* __restrict__ w1, const float* __restrict__ b1,
    const float* __restrict__ w2, const float* __restrict__ b2,
    u16* __restrict__ Smix)
{
  __shared__ float t0[32][33], t1[32][33], t0t[32][33], t1t[32][33];
  const int tid = threadIdx.x;
  const long long base = (long long)blockIdx.z*1024*1024;
  const int rb = blockIdx.y*32, cb = blockIdx.x*32;
  const int tx = tid&31, ty = tid>>5;
  #pragma unroll
  for (int rr=0;rr<4;rr++){
    int i = ty + rr*8;
    t0 [i][tx] = bf2f(S0[base + (long long)(rb+i)*1024 + cb+tx]);
    t1 [i][tx] = bf2f(S1[base + (long long)(rb+i)*1024 + cb+tx]);
    t0t[i][tx] = bf2f(S0[base + (long long)(cb+i)*1024 + rb+tx]);
    t1t[i][tx] = bf2f(S1[base + (long long)(cb+i)*1024 + rb+tx]);
  }
  __syncthreads();
  #pragma unroll 1
  for (int rr=0;rr<2;rr++){
    const int i0 = ty + rr*16, i1 = i0 + 8;
    f32x2 s0, s1v, s0t, s1t, cr, cl;
    s0[0]  = t0 [i0][tx]; s0[1]  = t0 [i1][tx];
    s1v[0] = t1 [i0][tx]; s1v[1] = t1 [i1][tx];
    s0t[0] = t0t[tx][i0]; s0t[1] = t0t[tx][i1];
    s1t[0] = t1t[tx][i0]; s1t[1] = t1t[tx][i1];
    long long off0 = base + (long long)(rb+i0)*1024 + cb+tx;
    long long off1 = base + (long long)(rb+i1)*1024 + cb+tx;
    cr[0] = bf2f(CRl[off0]); cr[1] = bf2f(CRl[off1]);
    cl[0] = bf2f(CLl[off0]); cl[1] = bf2f(CLl[off1]);
    f32x2 a0 = bc(b2[0]), a1 = bc(b2[1]), a2 = bc(b2[2]), a3 = bc(b2[3]);
    #pragma unroll 4
    for (int o=0;o<16;o++){
      f32x2 xx = pkfma(bc(w1[o*6+0]), s0,  bc(b1[o]));
      xx = pkfma(bc(w1[o*6+1]), s1v, xx);
      xx = pkfma(bc(w1[o*6+2]), s0t, xx);
      xx = pkfma(bc(w1[o*6+3]), s1t, xx);
      xx = pkfma(bc(w1[o*6+4]), cr,  xx);
      xx = pkfma(bc(w1[o*6+5]), cl,  xx);
      f32x2 xx2 = xx*xx;
      f32x2 u   = pkfma(bc(0.044715f), xx2, bc(1.f));
      f32x2 zz  = (xx*u) * bc(1.5957691f);
      zz = pkmin(pkmax(zz, bc(-3.f)), bc(3.f));
      f32x2 w   = pkfma(bc(-0.011008f), zz*zz, bc(0.25f));
      f32x2 p   = pkfma(zz, w, bc(0.5f));
      f32x2 hh  = xx*p;
      a0 = pkfma(bc(w2[o]),    hh, a0);
      a1 = pkfma(bc(w2[16+o]), hh, a1);
      a2 = pkfma(bc(w2[32+o]), hh, a2);
      a3 = pkfma(bc(w2[48+o]), hh, a3);
    }
    f32x2 g0, g1, g2, g3;
    { float E;
      E=__expf(a0[0]); g0[0]=E*(1.f-E);  E=__expf(a0[1]); g0[1]=E*(1.f-E);
      E=__expf(a1[0]); g1[0]=E*(1.f-E);  E=__expf(a1[1]); g1[1]=E*(1.f-E);
      E=__expf(a2[0]); g2[0]=E*(1.f-E);  E=__expf(a2[1]); g2[1]=E*(1.f-E);
      E=__expf(a3[0]); g3[0]=E*(1.f-E);  E=__expf(a3[1]); g3[1]=E*(1.f-E);
    }
    f32x2 mx = pkmax(s0, s1v);
    f32x2 dd = s0 - s1v;
    f32x2 ad = pkmax(dd, bc(0.f)-dd);
    f32x2 ee, lg;
    ee[0] = __expf(-ad[0]); ee[1] = __expf(-ad[1]);
    lg[0] = __logf(1.f+ee[0]); lg[1] = __logf(1.f+ee[1]);
    f32x2 lse = mx + lg;
    f32x2 smix = s0 + g0*s1v + g1*(lse - s0) - g2*(bc(0.5f)*s1v) + g3*cr;
    Smix[off0] = f2bf(smix[0]);
    Smix[off1] = f2bf(smix[1]);
  }
}

extern "C" void kernel_launch(void* const* d_in, const int* in_sizes, int n_in,
                              void* d_out, int out_size, void* d_ws, size_t ws_size,
                              hipStream_t stream)
{
  const float* x     = (const float*)d_in[0];
  const float* Wqkv0 = (const float*)d_in[1];
  const float* Wqkv1 = (const float*)d_in[2];
  const float* Wproj = (const float*)d_in[3];
  const float* c1w   = (const float*)d_in[4];
  const float* c1b   = (const float*)d_in[5];
  const float* c2w   = (const float*)d_in[6];
  const float* c2b   = (const float*)d_in[7];
  const float* logit = (const float*)d_in[8];

  char* ws = (char*)d_ws;
  size_t off = 0;
  auto alloc = [&](size_t bytes)->char*{ char* p = ws + off; off = (off + bytes + 255) & ~(size_t)255; return p; };

  const long long NN16 = 16LL*1024*1024;
  u16* xb  = (u16*)alloc(2048LL*512*2);
  u16* w0T = (u16*)alloc(1536LL*512*2);
  u16* w1T = (u16*)alloc(1536LL*512*2);
  u16* wpT = (u16*)alloc(512LL*512*2);
  u16* q0  = (u16*)alloc(16LL*1024*64*2);
  u16* k0  = (u16*)alloc(16LL*1024*64*2);
  u16* v0T = (u16*)alloc(16LL*1024*64*2);
  u16* q1  = (u16*)alloc(16LL*1024*64*2);
  u16* k1  = (u16*)alloc(16LL*1024*64*2);
  u16* v1T = (u16*)alloc(16LL*1024*64*2);  // pre-scaled by ys in QKV epilogue
  u16* S0b = (u16*)alloc(NN16*2);   // reused as Ab after gating
  u16* S1b = (u16*)alloc(NN16*2);   // reused as f32 split-K partials (16MB)
  u16* A0  = (u16*)alloc(NN16*2);
  u16* A1  = (u16*)alloc(NN16*2);   // reused as CRlog after CL GEMM
  u16* A0T = (u16*)alloc(NN16*2);   // reused as CR (raw C_fwd)
  u16* A1T = (u16*)alloc(NN16*2);   // reused as Smix
  u16* CL  = (u16*)alloc(NN16*2);   // log C_bwd
  u16* Yb  = (u16*)alloc(2048LL*512*2);

  u16* CR    = A0T;
  u16* CRlog = A1;
  u16* Smix  = A1T;
  u16* Ab    = S0b;
  float* Pyb = (float*)S1b;

  if (off > ws_size){
    fprintf(stderr, "kernel_launch: ws too small: need %zu have %zu\n", off, ws_size);
    return;
  }

  dim3 blk(256);

  // 1. casts
  cast_f32_bf16<<<dim3(262144/256), blk, 0, stream>>>(x, xb, 262144);
  castT_f32_bf16_2<<<dim3(48,16,2), blk, 0, stream>>>(Wqkv0, w0T, Wqkv1, w1T, 512, 1536);
  castT_f32_bf16<<<dim3(16,16), blk, 0, stream>>>(Wproj, wpT, 512, 512);

  // 2. QKV projections; v1 pre-scaled by ys=sigmoid(logit)
  gemm_bt<128,128,2,2,EPI_QKV,1><<<dim3(12,16,2), blk, 0, stream>>>(
      xb, w0T, xb, w1T, q0, k0, v0T, q1, k1, v1T, logit,
      512, 512, 512, 0, 0, 0, 0, 1);

  // 3. S0|S1
  gemm_bt<128,128,2,2,EPI_BF16,1><<<dim3(8,8,32), blk, 0, stream>>>(
      q0, k0, q1, k1, S0b, nullptr, nullptr, S1b, nullptr, nullptr, nullptr,
      64, 64, 64, 65536, 65536, 1048576, 1024, 16);

  // 4. fused softmax+transpose
  softmaxT<<<dim3(32,32), blk, 0, stream>>>(S0b, A0, A0T, S1b, A1, A1T);

  // 5. CL = log(A1@A0 + eps); then CR GEMM dual-writes raw C_fwd + log C_fwd
  gemm_bt<128,128,2,2,EPI_LOGBF16,0><<<dim3(8,8,16), blk, 0, stream>>>(
      A1, A0T, nullptr, nullptr, CL, nullptr, nullptr, nullptr, nullptr, nullptr, nullptr,
      1024, 1024, 1024, 1048576, 1048576, 1048576, 1024, 0);
  gemm_bt<128,128,2,2,EPI_RAWLOG,0><<<dim3(8,8,16), blk, 0, stream>>>(
      A0, A1T, nullptr, nullptr, CR, CRlog, nullptr, nullptr, nullptr, nullptr, nullptr,
      1024, 1024, 1024, 1048576, 1048576, 1048576, 1024, 0);

  // 6. gating -> Smix
  gating_kernel<<<dim3(32,32,16), blk, 0, stream>>>(S0b, S1b, CRlog, CL, c1w, c1b, c2w, c2b, Smix);

  // 7. A = softmax(Smix), wave-per-row
  softmax_wave<<<dim3(4096), blk, 0, stream>>>(Smix, Ab);

  // 8. Yb split-K: z = tile*4 + s; s<2: Ab@v0T chunk s; s>=2: CR@v1T chunk s-2
  gemm_bt<64,64,2,2,EPI_PF32,3><<<dim3(1,16,64), blk, 0, stream>>>(
      Ab, v0T, CR, v1T, Pyb, nullptr, nullptr, nullptr, nullptr, nullptr, nullptr,
      512, 1024, 1024, 1048576, 65536, 0, 0, 0);
  reduce4_yb<<<dim3(1024), blk, 0, stream>>>(Pyb, Yb);

  // 9. out = Y @ Wproj
  gemm_bt<64,64,2,2,EPI_F32,0><<<dim3(8,32,1), blk, 0, stream>>>(
      Yb, wpT, nullptr, nullptr, d_out, nullptr, nullptr, nullptr, nullptr, nullptr, nullptr,
      512, 512, 512, 0, 0, 0, 512, 0);

  (void)in_sizes; (void)n_in; (void)out_size;
}